// Round 1
// baseline (1431.094 us; speedup 1.0000x reference)
//
#include <hip/hip_runtime.h>
#include <hip/hip_bf16.h>
#include <math.h>

// Problem constants (from reference setup_inputs)
#define S_LEN 2048
#define B_SZ  4
#define E_DIM 512
#define H_NUM 8
#define HD    64
#define FF_DIM 2048
#define NROWS (S_LEN * B_SZ)   // 8192
#define WIN   128              // local_window_size

// ---------------------------------------------------------------------------
// 1) x + pos quirk: pos[:, :B, :] broadcast over seq -> x[s,b,e] += pos[b*E+e]
// ---------------------------------------------------------------------------
__global__ void add_pos_kernel(const float* __restrict__ x,
                               const float* __restrict__ pos,
                               float* __restrict__ xp) {
  int idx = blockIdx.x * blockDim.x + threadIdx.x;        // float4 index
  float4 xv = ((const float4*)x)[idx];
  // flat4 = s*(B*E/4) + b*(E/4) + e/4 ; pos index = flat4 % (B*E/4 = 512)
  float4 pv = ((const float4*)pos)[idx & 511];
  float4 o;
  o.x = xv.x + pv.x; o.y = xv.y + pv.y;
  o.z = xv.z + pv.z; o.w = xv.w + pv.w;
  ((float4*)xp)[idx] = o;
}

// ---------------------------------------------------------------------------
// 2) fp32 tiled GEMM: out[r][j] = sum_k A[r][k]*W[j][k] + bias[j]
//    A: M x K row-major, W: Nout x K row-major (torch Linear weight layout)
//    mode 0: plain  |  mode 1: relu  |  mode 2: scatter to q/k/v (B,H,S,hd)
// ---------------------------------------------------------------------------
#define BM 64
#define BN 64
#define BK 16

__global__ void gemm_kernel(const float* __restrict__ A,
                            const float* __restrict__ W,
                            const float* __restrict__ bias,
                            float* __restrict__ out,
                            int M, int Nout, int K, int mode,
                            float* __restrict__ qb, float* __restrict__ kb,
                            float* __restrict__ vb) {
  __shared__ float As[BK][BM];
  __shared__ float Bs[BK][BN];
  int tid = threadIdx.x;
  int tx = tid & 15, ty = tid >> 4;       // 16x16 thread tile, 4x4 outputs each
  int m0 = blockIdx.x * BM;
  int j0 = blockIdx.y * BN;

  int lm = tid >> 2;                      // 0..63 : tile row
  int lk = (tid & 3) << 2;                // 0,4,8,12 : k offset (float4)

  float acc[4][4] = {};

  for (int kt = 0; kt < K; kt += BK) {
    float4 av = *(const float4*)&A[(size_t)(m0 + lm) * K + kt + lk];
    float4 wv = *(const float4*)&W[(size_t)(j0 + lm) * K + kt + lk];
    As[lk + 0][lm] = av.x; As[lk + 1][lm] = av.y;
    As[lk + 2][lm] = av.z; As[lk + 3][lm] = av.w;
    Bs[lk + 0][lm] = wv.x; Bs[lk + 1][lm] = wv.y;
    Bs[lk + 2][lm] = wv.z; Bs[lk + 3][lm] = wv.w;
    __syncthreads();
#pragma unroll
    for (int kk = 0; kk < BK; kk++) {
      float4 a4 = *(const float4*)&As[kk][ty * 4];
      float4 b4 = *(const float4*)&Bs[kk][tx * 4];
      float ar[4] = {a4.x, a4.y, a4.z, a4.w};
      float br[4] = {b4.x, b4.y, b4.z, b4.w};
#pragma unroll
      for (int ii = 0; ii < 4; ii++)
#pragma unroll
        for (int jj = 0; jj < 4; jj++)
          acc[ii][jj] += ar[ii] * br[jj];
    }
    __syncthreads();
  }

#pragma unroll
  for (int ii = 0; ii < 4; ii++) {
    int r = m0 + ty * 4 + ii;
#pragma unroll
    for (int jj = 0; jj < 4; jj++) {
      int jg = j0 + tx * 4 + jj;
      float val = acc[ii][jj] + bias[jg];
      if (mode == 1) val = fmaxf(val, 0.f);
      if (mode == 2) {
        // qkv column jg -> which tensor / head / dim ; row r = s*B + b
        int which = jg >> 9;
        int e = jg & 511;
        int h = e >> 6, d = e & 63;
        int s = r >> 2, b = r & 3;
        float* dst = (which == 0) ? qb : (which == 1) ? kb : vb;
        dst[(((size_t)(b * H_NUM + h)) * S_LEN + s) * HD + d] = val;
      } else {
        out[(size_t)r * Nout + jg] = val;
      }
    }
  }
}

// ---------------------------------------------------------------------------
// 3) masked attention. allowed(i,j) = |i-j|<=128 || j%256==0.
//    One wave per (b,h,i) query row. Candidate list = contiguous window
//    [lo,hi] plus global columns outside the window (no double count).
//    nc <= 257 + 8 = 265 <= 320 = 5 slots x 64 lanes.
// ---------------------------------------------------------------------------
__global__ void attn_kernel(const float* __restrict__ q,
                            const float* __restrict__ k,
                            const float* __restrict__ v,
                            float* __restrict__ y) {
  __shared__ float qs[4][64];
  __shared__ float ps[4][320];
  __shared__ int   js[4][320];
  int wave = threadIdx.x >> 6;
  int lane = threadIdx.x & 63;
  int row = blockIdx.x * 4 + wave;        // [0, B*H*S)
  int bh = row >> 11;
  int i  = row & 2047;
  int b = bh >> 3, h = bh & 7;
  const float* kb = k + (size_t)bh * S_LEN * HD;
  const float* vb = v + (size_t)bh * S_LEN * HD;
  qs[wave][lane] = q[((size_t)bh * S_LEN + i) * HD + lane];
  __syncthreads();

  int lo = i - WIN; if (lo < 0) lo = 0;
  int hi = i + WIN; if (hi > S_LEN - 1) hi = S_LEN - 1;
  int wlen = hi - lo + 1;
  int nlow = (lo + 255) >> 8;             // globals 0..nlow-1 are below window
  int ghi0 = (hi >> 8) + 1;               // first global index above window
  int nhigh = (ghi0 < 8) ? (8 - ghi0) : 0;
  int nc = wlen + nlow + nhigh;

  float sc[5]; int jj[5];
#pragma unroll
  for (int t = 0; t < 5; t++) {
    int c = t * 64 + lane;
    float s = -INFINITY; int j = 0;
    if (c < nc) {
      if (c < wlen) j = lo + c;
      else {
        int idx = c - wlen;
        j = (idx < nlow) ? (idx << 8) : ((ghi0 + idx - nlow) << 8);
      }
      const float4* kr = (const float4*)(kb + (size_t)j * HD);
      float acc = 0.f;
#pragma unroll
      for (int d4 = 0; d4 < 16; d4++) {
        float4 kv4 = kr[d4];
        acc += qs[wave][d4 * 4 + 0] * kv4.x + qs[wave][d4 * 4 + 1] * kv4.y
             + qs[wave][d4 * 4 + 2] * kv4.z + qs[wave][d4 * 4 + 3] * kv4.w;
      }
      s = acc * 0.125f;                   // 1/sqrt(64)
    }
    sc[t] = s; jj[t] = j;
  }

  float m = fmaxf(fmaxf(fmaxf(sc[0], sc[1]), fmaxf(sc[2], sc[3])), sc[4]);
#pragma unroll
  for (int o = 32; o >= 1; o >>= 1) m = fmaxf(m, __shfl_xor(m, o, 64));

  float lsum = 0.f;
#pragma unroll
  for (int t = 0; t < 5; t++) {
    int c = t * 64 + lane;
    float p = (c < nc) ? __expf(sc[t] - m) : 0.f;
    lsum += p;
    ps[wave][c] = p;
    js[wave][c] = jj[t];
  }
#pragma unroll
  for (int o = 32; o >= 1; o >>= 1) lsum += __shfl_xor(lsum, o, 64);

  __syncthreads();   // make ps/js visible (also covers all 4 waves uniformly)

  float acc = 0.f;
#pragma unroll 4
  for (int c = 0; c < nc; c++) {
    float p = ps[wave][c];                // LDS broadcast
    int j = js[wave][c];
    acc += p * vb[(size_t)j * HD + lane]; // coalesced 256B per iteration
  }
  acc /= lsum;
  // y back to (S,B,E) for the out-proj GEMM
  y[(((size_t)i * B_SZ) + b) * E_DIM + h * HD + lane] = acc;
}

// ---------------------------------------------------------------------------
// 4) residual add + LayerNorm, one wave per row (E=512 -> 8 elems/lane)
// ---------------------------------------------------------------------------
__global__ void add_ln_kernel(const float* __restrict__ a,
                              const float* __restrict__ r,
                              const float* __restrict__ g,
                              const float* __restrict__ be,
                              float* __restrict__ out) {
  int wave = threadIdx.x >> 6;
  int lane = threadIdx.x & 63;
  int row = blockIdx.x * 4 + wave;
  const float* ar = a + (size_t)row * E_DIM;
  const float* rr = r + (size_t)row * E_DIM;
  float vals[8];
  float s = 0.f;
#pragma unroll
  for (int t = 0; t < 8; t++) {
    vals[t] = ar[t * 64 + lane] + rr[t * 64 + lane];
    s += vals[t];
  }
#pragma unroll
  for (int o = 32; o >= 1; o >>= 1) s += __shfl_xor(s, o, 64);
  float mu = s * (1.f / E_DIM);
  float vs = 0.f;
#pragma unroll
  for (int t = 0; t < 8; t++) { float d = vals[t] - mu; vs += d * d; }
#pragma unroll
  for (int o = 32; o >= 1; o >>= 1) vs += __shfl_xor(vs, o, 64);
  float inv = rsqrtf(vs * (1.f / E_DIM) + 1e-5f);
  float* orow = out + (size_t)row * E_DIM;
#pragma unroll
  for (int t = 0; t < 8; t++) {
    int e = t * 64 + lane;
    orow[e] = (vals[t] - mu) * inv * g[e] + be[e];
  }
}

// ---------------------------------------------------------------------------
// launch
// ---------------------------------------------------------------------------
extern "C" void kernel_launch(void* const* d_in, const int* in_sizes, int n_in,
                              void* d_out, int out_size, void* d_ws, size_t ws_size,
                              hipStream_t stream) {
  const float* x     = (const float*)d_in[0];
  const float* pos   = (const float*)d_in[1];
  const float* in_w  = (const float*)d_in[2];
  const float* in_b  = (const float*)d_in[3];
  const float* out_w = (const float*)d_in[4];
  const float* out_b = (const float*)d_in[5];
  const float* w1    = (const float*)d_in[6];
  const float* b1    = (const float*)d_in[7];
  const float* w2    = (const float*)d_in[8];
  const float* b2    = (const float*)d_in[9];
  const float* g1    = (const float*)d_in[10];
  const float* be1   = (const float*)d_in[11];
  const float* g2    = (const float*)d_in[12];
  const float* be2   = (const float*)d_in[13];
  float* out = (float*)d_out;

  // workspace layout (floats). Peak = 24M floats = 96 MB.
  //   xp   [0, 4M)       x+pos, kept as LN1 residual; LN1 writes x1 in-place
  //   q    [4M, 8M)      (B,H,S,hd)
  //   k    [8M, 12M)
  //   v    [12M, 16M)
  //   y    [16M, 20M)    attention out (S,B,E)
  //   aprj [20M, 24M)    out-proj result; later reused as ff2
  //   ff1  [4M, 20M)     reuses q/k/v/y after attention is consumed
  float* ws = (float*)d_ws;
  const size_t M1 = (size_t)1024 * 1024;
  float* xp   = ws;
  float* qb   = ws + 4 * M1;
  float* kb   = ws + 8 * M1;
  float* vb   = ws + 12 * M1;
  float* yb   = ws + 16 * M1;
  float* aprj = ws + 20 * M1;
  float* ff1  = ws + 4 * M1;
  float* ff2  = ws + 20 * M1;
  float* x1   = xp;   // LN1 in-place over xp (each wave reads its row into
                      // registers before writing; rows are independent)

  // 1) x + pos
  add_pos_kernel<<<4096, 256, 0, stream>>>(x, pos, xp);
  // 2) QKV GEMM + head scatter
  gemm_kernel<<<dim3(NROWS / 64, 1536 / 64), 256, 0, stream>>>(
      xp, in_w, in_b, nullptr, NROWS, 1536, E_DIM, 2, qb, kb, vb);
  // 3) masked attention
  attn_kernel<<<(B_SZ * H_NUM * S_LEN) / 4, 256, 0, stream>>>(qb, kb, vb, yb);
  // 4) out projection
  gemm_kernel<<<dim3(NROWS / 64, E_DIM / 64), 256, 0, stream>>>(
      yb, out_w, out_b, aprj, NROWS, E_DIM, E_DIM, 0, nullptr, nullptr, nullptr);
  // 5) LN1 (residual = xp), in-place -> x1
  add_ln_kernel<<<NROWS / 4, 256, 0, stream>>>(xp, aprj, g1, be1, x1);
  // 6) FF1 + relu
  gemm_kernel<<<dim3(NROWS / 64, FF_DIM / 64), 256, 0, stream>>>(
      x1, w1, b1, ff1, NROWS, FF_DIM, E_DIM, 1, nullptr, nullptr, nullptr);
  // 7) FF2
  gemm_kernel<<<dim3(NROWS / 64, E_DIM / 64), 256, 0, stream>>>(
      ff1, w2, b2, ff2, NROWS, E_DIM, FF_DIM, 0, nullptr, nullptr, nullptr);
  // 8) LN2 -> output
  add_ln_kernel<<<NROWS / 4, 256, 0, stream>>>(x1, ff2, g2, be2, out);
}

// Round 2
// 371.596 us; speedup vs baseline: 3.8512x; 3.8512x over previous
//
#include <hip/hip_runtime.h>
#include <hip/hip_bf16.h>
#include <math.h>

#define S_LEN 2048
#define B_SZ  4
#define E_DIM 512
#define H_NUM 8
#define HD    64
#define FF_DIM 2048
#define NROWS 8192
#define WIN   128

typedef unsigned short u16;
typedef __bf16 bf16x8 __attribute__((ext_vector_type(8)));
typedef float  f32x4  __attribute__((ext_vector_type(4)));

// fp32 -> bf16 round-to-nearest-even (bit manipulation; avoids API variance)
__device__ __forceinline__ u16 f2bf(float f) {
  union { float f; unsigned u; } v; v.f = f;
  unsigned u = v.u;
  return (u16)((u + 0x7fffu + ((u >> 16) & 1u)) >> 16);
}

// ---------------------------------------------------------------------------
// weight cast: 4 fp32 matrices -> bf16, one launch, f4-granular
// sizes (f4): in_w 196608 | out_w 65536 | w1 262144 | w2 262144  -> 786432
// ---------------------------------------------------------------------------
__global__ __launch_bounds__(256) void wcast_kernel(
    const float* __restrict__ s0, const float* __restrict__ s1,
    const float* __restrict__ s2, const float* __restrict__ s3,
    u16* __restrict__ d0, u16* __restrict__ d1,
    u16* __restrict__ d2, u16* __restrict__ d3) {
  const int n0 = 196608, n1 = 65536, n2 = 262144;
  int i = blockIdx.x * blockDim.x + threadIdx.x;   // grid sized exactly
  const float4* sp; ushort4* dp; int off;
  if (i < n0)                { sp = (const float4*)s0; dp = (ushort4*)d0; off = i; }
  else if (i < n0 + n1)      { sp = (const float4*)s1; dp = (ushort4*)d1; off = i - n0; }
  else if (i < n0 + n1 + n2) { sp = (const float4*)s2; dp = (ushort4*)d2; off = i - n0 - n1; }
  else                       { sp = (const float4*)s3; dp = (ushort4*)d3; off = i - n0 - n1 - n2; }
  float4 v = sp[off];
  ushort4 o; o.x = f2bf(v.x); o.y = f2bf(v.y); o.z = f2bf(v.z); o.w = f2bf(v.w);
  dp[off] = o;
}

// ---------------------------------------------------------------------------
// x + pos (pos[:, :B, :] broadcast over seq) -> fp32 + bf16 copies
// ---------------------------------------------------------------------------
__global__ __launch_bounds__(256) void add_pos_kernel(
    const float* __restrict__ x, const float* __restrict__ pos,
    float* __restrict__ xp, u16* __restrict__ xpb) {
  int idx = blockIdx.x * blockDim.x + threadIdx.x;
  float4 xv = ((const float4*)x)[idx];
  float4 pv = ((const float4*)pos)[idx & 511];     // (B*E/4)=512 f4 period
  float4 o;
  o.x = xv.x + pv.x; o.y = xv.y + pv.y; o.z = xv.z + pv.z; o.w = xv.w + pv.w;
  ((float4*)xp)[idx] = o;
  ushort4 ob; ob.x = f2bf(o.x); ob.y = f2bf(o.y); ob.z = f2bf(o.z); ob.w = f2bf(o.w);
  ((ushort4*)xpb)[idx] = ob;
}

// ---------------------------------------------------------------------------
// bf16 MFMA GEMM (m97-style, single-buffered LDS staging):
//   C[m][n] = sum_k A[m][k] * W[n][k] + bias[n]
// A: M x K bf16 row-major, W: N x K bf16 row-major (torch Linear layout).
// 128x128 tile, BK=64, 4 waves (2x2 of 64x64), 16x16x32 MFMA, 4x4 tiles/wave.
// mode 0: fp32 out | mode 1: relu -> bf16 out | mode 2: scatter q/k/v fp32
// ---------------------------------------------------------------------------
#define GBM 128
#define GBK 64

__global__ __launch_bounds__(256) void mfma_gemm(
    const u16* __restrict__ A, const u16* __restrict__ W,
    const float* __restrict__ bias, float* __restrict__ outf,
    u16* __restrict__ outb, int M, int N, int K, int mode,
    float* __restrict__ qb, float* __restrict__ kb, float* __restrict__ vb) {
  __shared__ u16 As[GBM * GBK];
  __shared__ u16 Bs[GBM * GBK];
  int tid = threadIdx.x;
  int lane = tid & 63;
  int w = tid >> 6;
  int m0 = blockIdx.x * GBM;
  int j0 = blockIdx.y * GBM;
  int wrow = (w >> 1) * 64;
  int wcol = (w & 1) * 64;
  int lm = lane & 15;     // A/B fragment row (m or n)
  int kq = lane >> 4;     // k-quad

  f32x4 acc[4][4];
#pragma unroll
  for (int i = 0; i < 4; i++)
#pragma unroll
    for (int j = 0; j < 4; j++) acc[i][j] = (f32x4){0.f, 0.f, 0.f, 0.f};

  const u16* Ab = A + (size_t)m0 * K;
  const u16* Wb = W + (size_t)j0 * K;

  for (int kt = 0; kt < K; kt += GBK) {
    __syncthreads();                    // previous iter's reads done
#pragma unroll
    for (int u = 0; u < 4; u++) {       // 1024 16B-chunks over 256 threads
      int flat = u * 256 + tid;
      int r = flat >> 3, c8 = (flat & 7) * 8;
      *(uint4*)&As[r * GBK + c8] = *(const uint4*)&Ab[(size_t)r * K + kt + c8];
      *(uint4*)&Bs[r * GBK + c8] = *(const uint4*)&Wb[(size_t)r * K + kt + c8];
    }
    __syncthreads();
#pragma unroll
    for (int k2 = 0; k2 < GBK; k2 += 32) {
      bf16x8 af[4], bfr[4];
#pragma unroll
      for (int t = 0; t < 4; t++) {
        af[t]  = *(const bf16x8*)&As[(wrow + t * 16 + lm) * GBK + k2 + kq * 8];
        bfr[t] = *(const bf16x8*)&Bs[(wcol + t * 16 + lm) * GBK + k2 + kq * 8];
      }
#pragma unroll
      for (int ti = 0; ti < 4; ti++)
#pragma unroll
        for (int tj = 0; tj < 4; tj++)
          acc[ti][tj] = __builtin_amdgcn_mfma_f32_16x16x32_bf16(
              af[ti], bfr[tj], acc[ti][tj], 0, 0, 0);
    }
  }

  // epilogue: C/D layout col=lane&15, row=(lane>>4)*4+reg
#pragma unroll
  for (int tj = 0; tj < 4; tj++) {
    int n = j0 + wcol + tj * 16 + lm;
    float bv = bias[n];
#pragma unroll
    for (int ti = 0; ti < 4; ti++) {
#pragma unroll
      for (int r = 0; r < 4; r++) {
        int m = m0 + wrow + ti * 16 + kq * 4 + r;
        float val = acc[ti][tj][r] + bv;
        if (mode == 0) {
          outf[(size_t)m * N + n] = val;
        } else if (mode == 1) {
          outb[(size_t)m * N + n] = f2bf(fmaxf(val, 0.f));
        } else {
          int which = n >> 9, e = n & 511, h = e >> 6, d = e & 63;
          int s = m >> 2, b = m & 3;
          float* dst = (which == 0) ? qb : (which == 1) ? kb : vb;
          dst[(((size_t)(b * H_NUM + h)) * S_LEN + s) * HD + d] = val;
        }
      }
    }
  }
}

// ---------------------------------------------------------------------------
// tiled attention: block = one (b,h) x 64-query tile, 256 threads.
// Window [cl,chi] (multiple of 64 cols) chunked by 64, + one globals chunk.
// Flash online softmax; QK^T and PV are 64x64x64 fp32 micro-GEMMs
// (4x4 per thread, 16x16 thread grid). K staged transposed; P reuses K buffer.
// ---------------------------------------------------------------------------
#define AST 68   // LDS row stride (floats): 16B-aligned, conflict-light

__global__ __launch_bounds__(256) void attn_tile_kernel(
    const float* __restrict__ q, const float* __restrict__ k,
    const float* __restrict__ v, u16* __restrict__ yb) {
  __shared__ float Qs[64 * AST];    // Qs[d][q] (transposed, pre-scaled)
  __shared__ float KPs[64 * AST];   // Ks[d][c]  then  Ps[c][q]
  __shared__ float Vs[64 * AST];    // Vs[c][d]
  int tid = threadIdx.x;
  int tx = tid & 15, ty = tid >> 4;
  int i0 = blockIdx.x * 64;
  int bh = blockIdx.y;
  int b = bh >> 3, h = bh & 7;
  const float* qp = q + ((size_t)bh * S_LEN + i0) * HD;
  const float* kp = k + (size_t)bh * S_LEN * HD;
  const float* vp = v + (size_t)bh * S_LEN * HD;

  int cl = i0 - WIN; if (cl < 0) cl = 0;
  int chi = i0 + 63 + WIN; if (chi > S_LEN - 1) chi = S_LEN - 1;
  int nch = (chi - cl + 64) >> 6;           // window chunks (length mult of 64)
  int tlo = (cl + 255) >> 8;                // globals below window
  int thi0 = (chi >> 8) + 1;                // first global above window
  int ng = tlo + (8 - thi0);                // globals outside window (6..8)

  // stage Q transposed, folded scale 1/sqrt(64)
  {
    int qq = tid >> 2, f4b = tid & 3;
#pragma unroll
    for (int jj = 0; jj < 4; jj++) {
      int d0 = (f4b + 4 * jj) * 4;
      float4 val = *(const float4*)&qp[qq * HD + d0];
      Qs[(d0 + 0) * AST + qq] = val.x * 0.125f;
      Qs[(d0 + 1) * AST + qq] = val.y * 0.125f;
      Qs[(d0 + 2) * AST + qq] = val.z * 0.125f;
      Qs[(d0 + 3) * AST + qq] = val.w * 0.125f;
    }
  }

  float m_i[4], l_i[4], o[4][4];
#pragma unroll
  for (int i = 0; i < 4; i++) {
    m_i[i] = -INFINITY; l_i[i] = 0.f;
#pragma unroll
    for (int j = 0; j < 4; j++) o[i][j] = 0.f;
  }

  for (int ch = 0; ch <= nch; ch++) {       // ch == nch -> globals chunk
    bool is_g = (ch == nch);
    int c0 = cl + ch * 64;
    __syncthreads();                        // prev PV done; Q visible (iter 0)
    {                                       // stage K^T and V for this chunk
      int cc = tid >> 2, f4b = tid & 3;
      int src_row; bool valid;
      if (!is_g) { src_row = c0 + cc; valid = (src_row <= chi); }
      else {
        valid = (cc < ng);
        src_row = valid ? ((cc < tlo) ? cc * 256 : (thi0 + cc - tlo) * 256) : 0;
      }
#pragma unroll
      for (int jj = 0; jj < 4; jj++) {
        int d0 = (f4b + 4 * jj) * 4;
        float4 kv = make_float4(0.f, 0.f, 0.f, 0.f);
        float4 vv = make_float4(0.f, 0.f, 0.f, 0.f);
        if (valid) {
          kv = *(const float4*)&kp[(size_t)src_row * HD + d0];
          vv = *(const float4*)&vp[(size_t)src_row * HD + d0];
        }
        KPs[(d0 + 0) * AST + cc] = kv.x;
        KPs[(d0 + 1) * AST + cc] = kv.y;
        KPs[(d0 + 2) * AST + cc] = kv.z;
        KPs[(d0 + 3) * AST + cc] = kv.w;
        *(float4*)&Vs[cc * AST + d0] = vv;
      }
    }
    __syncthreads();

    // S[q][c] micro-GEMM: rows q=ty*4+i, cols c=tx*4+j
    float s[4][4] = {};
    for (int kk = 0; kk < 64; kk++) {
      float4 a4 = *(const float4*)&Qs[kk * AST + ty * 4];
      float4 b4 = *(const float4*)&KPs[kk * AST + tx * 4];
      float ar[4] = {a4.x, a4.y, a4.z, a4.w};
      float br[4] = {b4.x, b4.y, b4.z, b4.w};
#pragma unroll
      for (int i = 0; i < 4; i++)
#pragma unroll
        for (int j = 0; j < 4; j++) s[i][j] += ar[i] * br[j];
    }
    // mask invalid cols
#pragma unroll
    for (int j = 0; j < 4; j++) {
      int cidx = tx * 4 + j;
      bool inval = is_g ? (cidx >= ng) : (c0 + cidx > chi);
      if (inval) {
#pragma unroll
        for (int i = 0; i < 4; i++) s[i][j] = -INFINITY;
      }
    }
    // online softmax (state replicated across tx lanes; reductions over tx)
    float alpha[4];
#pragma unroll
    for (int i = 0; i < 4; i++) {
      float mx = fmaxf(fmaxf(s[i][0], s[i][1]), fmaxf(s[i][2], s[i][3]));
#pragma unroll
      for (int off = 8; off >= 1; off >>= 1) mx = fmaxf(mx, __shfl_xor(mx, off, 64));
      float mnew = fmaxf(m_i[i], mx);
      alpha[i] = __expf(m_i[i] - mnew);
      float rs = 0.f;
#pragma unroll
      for (int j = 0; j < 4; j++) { float p = __expf(s[i][j] - mnew); s[i][j] = p; rs += p; }
#pragma unroll
      for (int off = 8; off >= 1; off >>= 1) rs += __shfl_xor(rs, off, 64);
      l_i[i] = l_i[i] * alpha[i] + rs;
      m_i[i] = mnew;
#pragma unroll
      for (int j = 0; j < 4; j++) o[i][j] *= alpha[i];
    }
    __syncthreads();                        // all waves done reading K data
    // write P into KPs as Ps[c][q]
#pragma unroll
    for (int i = 0; i < 4; i++)
#pragma unroll
      for (int j = 0; j < 4; j++)
        KPs[(tx * 4 + j) * AST + ty * 4 + i] = s[i][j];
    __syncthreads();
    // PV micro-GEMM: O[q][d] += sum_c Ps[c][q] * Vs[c][d]
    for (int kk = 0; kk < 64; kk++) {
      float4 a4 = *(const float4*)&KPs[kk * AST + ty * 4];
      float4 b4 = *(const float4*)&Vs[kk * AST + tx * 4];
      float ar[4] = {a4.x, a4.y, a4.z, a4.w};
      float br[4] = {b4.x, b4.y, b4.z, b4.w};
#pragma unroll
      for (int i = 0; i < 4; i++)
#pragma unroll
        for (int j = 0; j < 4; j++) o[i][j] += ar[i] * br[j];
    }
  }

  // epilogue -> y (S,B,E) as bf16 (feeds out-proj GEMM only)
#pragma unroll
  for (int i = 0; i < 4; i++) {
    int s_glob = i0 + ty * 4 + i;
    float inv = 1.f / l_i[i];
    ushort4 w4;
    w4.x = f2bf(o[i][0] * inv); w4.y = f2bf(o[i][1] * inv);
    w4.z = f2bf(o[i][2] * inv); w4.w = f2bf(o[i][3] * inv);
    *(ushort4*)&yb[(((size_t)s_glob * B_SZ + b) * E_DIM) + h * HD + tx * 4] = w4;
  }
}

// ---------------------------------------------------------------------------
// residual add + LayerNorm; optional bf16 secondary output
// ---------------------------------------------------------------------------
__global__ __launch_bounds__(256) void add_ln_kernel(
    const float* __restrict__ a, const float* __restrict__ r,
    const float* __restrict__ g, const float* __restrict__ be,
    float* __restrict__ out, u16* __restrict__ outb) {
  int wave = threadIdx.x >> 6;
  int lane = threadIdx.x & 63;
  int row = blockIdx.x * 4 + wave;
  const float* ar = a + (size_t)row * E_DIM;
  const float* rr = r + (size_t)row * E_DIM;
  float vals[8];
  float s = 0.f;
#pragma unroll
  for (int t = 0; t < 8; t++) {
    vals[t] = ar[t * 64 + lane] + rr[t * 64 + lane];
    s += vals[t];
  }
#pragma unroll
  for (int o = 32; o >= 1; o >>= 1) s += __shfl_xor(s, o, 64);
  float mu = s * (1.f / E_DIM);
  float vs = 0.f;
#pragma unroll
  for (int t = 0; t < 8; t++) { float d = vals[t] - mu; vs += d * d; }
#pragma unroll
  for (int o = 32; o >= 1; o >>= 1) vs += __shfl_xor(vs, o, 64);
  float inv = rsqrtf(vs * (1.f / E_DIM) + 1e-5f);
  float* orow = out + (size_t)row * E_DIM;
  u16* obrow = outb ? outb + (size_t)row * E_DIM : nullptr;
#pragma unroll
  for (int t = 0; t < 8; t++) {
    int e = t * 64 + lane;
    float val = (vals[t] - mu) * inv * g[e] + be[e];
    orow[e] = val;
    if (obrow) obrow[e] = f2bf(val);
  }
}

// ---------------------------------------------------------------------------
// launch
// ---------------------------------------------------------------------------
extern "C" void kernel_launch(void* const* d_in, const int* in_sizes, int n_in,
                              void* d_out, int out_size, void* d_ws, size_t ws_size,
                              hipStream_t stream) {
  const float* x     = (const float*)d_in[0];
  const float* pos   = (const float*)d_in[1];
  const float* in_w  = (const float*)d_in[2];
  const float* in_b  = (const float*)d_in[3];
  const float* out_w = (const float*)d_in[4];
  const float* out_b = (const float*)d_in[5];
  const float* w1    = (const float*)d_in[6];
  const float* b1    = (const float*)d_in[7];
  const float* w2    = (const float*)d_in[8];
  const float* b2    = (const float*)d_in[9];
  const float* g1    = (const float*)d_in[10];
  const float* be1   = (const float*)d_in[11];
  const float* g2    = (const float*)d_in[12];
  const float* be2   = (const float*)d_in[13];
  float* out = (float*)d_out;

  // workspace (87 MB peak, byte offsets):
  //   0    xp fp32 (16MB)        -> x1 in-place after LN1
  //   16M  xpb bf16 (8MB)        -> x1b after LN1
  //   24M  q fp32 (16MB)         -> aprj after attn -> ff2 after LN1
  //   40M  k fp32 (16MB)  \
  //   56M  v fp32 (16MB)  /      -> ff1b bf16 (32MB) after attn
  //   72M  ybf bf16 (8MB)
  //   80M  in_wb | 82M out_wb | 83M w1b | 85M w2b  (bf16 weights)
  char* base = (char*)d_ws;
  float* xp    = (float*)(base);
  u16*   xpb   = (u16*)(base + ((size_t)16 << 20));
  float* qb    = (float*)(base + ((size_t)24 << 20));
  float* kb    = (float*)(base + ((size_t)40 << 20));
  float* vb    = (float*)(base + ((size_t)56 << 20));
  u16*   ybf   = (u16*)(base + ((size_t)72 << 20));
  u16*   inwb  = (u16*)(base + ((size_t)80 << 20));
  u16*   outwb = (u16*)(base + ((size_t)82 << 20));
  u16*   w1b   = (u16*)(base + ((size_t)83 << 20));
  u16*   w2b   = (u16*)(base + ((size_t)85 << 20));
  float* aprj  = qb;
  float* x1    = xp;
  u16*   x1b   = xpb;
  u16*   ff1b  = (u16*)(base + ((size_t)40 << 20));
  float* ff2   = qb;

  wcast_kernel<<<3072, 256, 0, stream>>>(in_w, out_w, w1, w2, inwb, outwb, w1b, w2b);
  add_pos_kernel<<<4096, 256, 0, stream>>>(x, pos, xp, xpb);
  mfma_gemm<<<dim3(64, 12), 256, 0, stream>>>(xpb, inwb, in_b, nullptr, nullptr,
                                              NROWS, 1536, 512, 2, qb, kb, vb);
  attn_tile_kernel<<<dim3(32, 32), 256, 0, stream>>>(qb, kb, vb, ybf);
  mfma_gemm<<<dim3(64, 4), 256, 0, stream>>>(ybf, outwb, out_b, aprj, nullptr,
                                             NROWS, 512, 512, 0, nullptr, nullptr, nullptr);
  add_ln_kernel<<<2048, 256, 0, stream>>>(xp, aprj, g1, be1, x1, x1b);
  mfma_gemm<<<dim3(64, 16), 256, 0, stream>>>(x1b, w1b, b1, nullptr, ff1b,
                                              NROWS, 2048, 512, 1, nullptr, nullptr, nullptr);
  mfma_gemm<<<dim3(64, 4), 256, 0, stream>>>(ff1b, w2b, b2, ff2, nullptr,
                                             NROWS, 512, 2048, 0, nullptr, nullptr, nullptr);
  add_ln_kernel<<<2048, 256, 0, stream>>>(x1, ff2, g2, be2, out, nullptr);
}

// Round 3
// 310.870 us; speedup vs baseline: 4.6035x; 1.1953x over previous
//
#include <hip/hip_runtime.h>
#include <hip/hip_bf16.h>
#include <math.h>

#define S_LEN 2048
#define B_SZ  4
#define E_DIM 512
#define H_NUM 8
#define HD    64
#define FF_DIM 2048
#define NROWS 8192
#define WIN   128

typedef unsigned short u16;
typedef __bf16 bf16x8 __attribute__((ext_vector_type(8)));
typedef float  f32x4  __attribute__((ext_vector_type(4)));

// fp32 -> bf16 round-to-nearest-even
__device__ __forceinline__ u16 f2bf(float f) {
  union { float f; unsigned u; } v; v.f = f;
  unsigned u = v.u;
  return (u16)((u + 0x7fffu + ((u >> 16) & 1u)) >> 16);
}

// async global->LDS, 16B per lane; LDS dest = wave-uniform base + lane*16
__device__ __forceinline__ void gl_lds16(const u16* gp, u16* lp) {
  __builtin_amdgcn_global_load_lds(
      (const __attribute__((address_space(1))) unsigned int*)gp,
      (__attribute__((address_space(3))) unsigned int*)lp, 16, 0, 0);
}

// ---------------------------------------------------------------------------
// weight cast: 4 fp32 matrices -> bf16
// ---------------------------------------------------------------------------
__global__ __launch_bounds__(256) void wcast_kernel(
    const float* __restrict__ s0, const float* __restrict__ s1,
    const float* __restrict__ s2, const float* __restrict__ s3,
    u16* __restrict__ d0, u16* __restrict__ d1,
    u16* __restrict__ d2, u16* __restrict__ d3) {
  const int n0 = 196608, n1 = 65536, n2 = 262144;
  int i = blockIdx.x * blockDim.x + threadIdx.x;
  const float4* sp; ushort4* dp; int off;
  if (i < n0)                { sp = (const float4*)s0; dp = (ushort4*)d0; off = i; }
  else if (i < n0 + n1)      { sp = (const float4*)s1; dp = (ushort4*)d1; off = i - n0; }
  else if (i < n0 + n1 + n2) { sp = (const float4*)s2; dp = (ushort4*)d2; off = i - n0 - n1; }
  else                       { sp = (const float4*)s3; dp = (ushort4*)d3; off = i - n0 - n1 - n2; }
  float4 v = sp[off];
  ushort4 o; o.x = f2bf(v.x); o.y = f2bf(v.y); o.z = f2bf(v.z); o.w = f2bf(v.w);
  dp[off] = o;
}

// ---------------------------------------------------------------------------
// x + pos (pos[:, :B, :] broadcast over seq) -> fp32 + bf16 copies
// ---------------------------------------------------------------------------
__global__ __launch_bounds__(256) void add_pos_kernel(
    const float* __restrict__ x, const float* __restrict__ pos,
    float* __restrict__ xp, u16* __restrict__ xpb) {
  int idx = blockIdx.x * blockDim.x + threadIdx.x;
  float4 xv = ((const float4*)x)[idx];
  float4 pv = ((const float4*)pos)[idx & 511];
  float4 o;
  o.x = xv.x + pv.x; o.y = xv.y + pv.y; o.z = xv.z + pv.z; o.w = xv.w + pv.w;
  ((float4*)xp)[idx] = o;
  ushort4 ob; ob.x = f2bf(o.x); ob.y = f2bf(o.y); ob.z = f2bf(o.z); ob.w = f2bf(o.w);
  ((ushort4*)xpb)[idx] = ob;
}

// ---------------------------------------------------------------------------
// bf16 MFMA GEMM, m97-style: 128x128 tile, BK=64, global_load_lds width=16.
// mode 0: fp32 out | mode 1: relu -> bf16 out | mode 2: scatter q(scaled)/k/vT
// ---------------------------------------------------------------------------
#define GBK 64

__global__ __launch_bounds__(256) void mfma_gemm(
    const u16* __restrict__ A, const u16* __restrict__ W,
    const float* __restrict__ bias, float* __restrict__ outf,
    u16* __restrict__ outb, int M, int N, int K, int mode,
    u16* __restrict__ qb, u16* __restrict__ kb, u16* __restrict__ vtb) {
  __shared__ u16 As[128 * GBK];
  __shared__ u16 Bs[128 * GBK];
  int tid = threadIdx.x;
  int lane = tid & 63;
  int w = tid >> 6;
  int m0 = blockIdx.x * 128;
  int j0 = blockIdx.y * 128;
  int wrow = (w >> 1) * 64;
  int wcol = (w & 1) * 64;
  int lm = lane & 15;
  int kq = lane >> 4;

  f32x4 acc[4][4];
#pragma unroll
  for (int i = 0; i < 4; i++)
#pragma unroll
    for (int j = 0; j < 4; j++) acc[i][j] = (f32x4){0.f, 0.f, 0.f, 0.f};

  const u16* Ab = A + (size_t)m0 * K;
  const u16* Wb = W + (size_t)j0 * K;

  for (int kt = 0; kt < K; kt += GBK) {
    __syncthreads();
#pragma unroll
    for (int u = 0; u < 4; u++) {          // 16 segs of 1024B per tile
      int seg = u * 4 + w;
      int chunk = seg * 64 + lane;
      int r = chunk >> 3, c = (chunk & 7) << 3;
      gl_lds16(&Ab[(size_t)r * K + kt + c], &As[seg * 512]);
      gl_lds16(&Wb[(size_t)r * K + kt + c], &Bs[seg * 512]);
    }
    __syncthreads();
#pragma unroll
    for (int k2 = 0; k2 < GBK; k2 += 32) {
      bf16x8 af[4], bfr[4];
#pragma unroll
      for (int t = 0; t < 4; t++) {
        af[t]  = *(const bf16x8*)&As[(wrow + t * 16 + lm) * GBK + k2 + kq * 8];
        bfr[t] = *(const bf16x8*)&Bs[(wcol + t * 16 + lm) * GBK + k2 + kq * 8];
      }
#pragma unroll
      for (int ti = 0; ti < 4; ti++)
#pragma unroll
        for (int tj = 0; tj < 4; tj++)
          acc[ti][tj] = __builtin_amdgcn_mfma_f32_16x16x32_bf16(
              af[ti], bfr[tj], acc[ti][tj], 0, 0, 0);
    }
  }

  // C/D layout: col=lane&15, row=(lane>>4)*4+reg
#pragma unroll
  for (int tj = 0; tj < 4; tj++) {
    int n = j0 + wcol + tj * 16 + lm;
    float bv = bias[n];
#pragma unroll
    for (int ti = 0; ti < 4; ti++) {
#pragma unroll
      for (int r = 0; r < 4; r++) {
        int m = m0 + wrow + ti * 16 + kq * 4 + r;
        float val = acc[ti][tj][r] + bv;
        if (mode == 0) {
          outf[(size_t)m * N + n] = val;
        } else if (mode == 1) {
          outb[(size_t)m * N + n] = f2bf(fmaxf(val, 0.f));
        } else {
          int which = n >> 9, e = n & 511, h = e >> 6, d = e & 63;
          int s = m >> 2, b = m & 3;
          int bh = b * H_NUM + h;
          if (which == 0)       // q pre-scaled by 1/sqrt(hd)
            qb[((size_t)bh * S_LEN + s) * HD + d] = f2bf(val * 0.125f);
          else if (which == 1)
            kb[((size_t)bh * S_LEN + s) * HD + d] = f2bf(val);
          else                  // v stored transposed (b,h,d,s)
            vtb[((size_t)bh * HD + d) * S_LEN + s] = f2bf(val);
        }
      }
    }
  }
}

// ---------------------------------------------------------------------------
// MFMA attention: block = (64 queries) x (b,h); 4 waves; wave w owns query
// rows [16w,16w+16). Per 64-key chunk: QK^T (8 mfma/wave) -> online softmax
// (C-layout regs, 16-lane shuffles) -> P via LDS -> PV (8 mfma/wave).
// K/V^T/Q staged with global_load_lds; V pre-transposed in global (b,h,d,s).
// ---------------------------------------------------------------------------
#define PST 72   // Ps row stride (u16): 144B = 16B-aligned, breaks pow2 banks

__global__ __launch_bounds__(256) void attn_mfma_kernel(
    const u16* __restrict__ q, const u16* __restrict__ k,
    const u16* __restrict__ vt, u16* __restrict__ yb) {
  __shared__ u16 Qs[64 * 64];   // [q][d]
  __shared__ u16 Ks[64 * 64];   // [c][d]
  __shared__ u16 Vs[64 * 64];   // [d][c]
  __shared__ u16 Ps[64 * PST];  // [q][c] bf16
  int tid = threadIdx.x, lane = tid & 63, w = tid >> 6;
  int quad = lane >> 4, lm = lane & 15;
  int i0 = blockIdx.x * 64, bh = blockIdx.y;
  int b = bh >> 3, h = bh & 7;
  const u16* qp = q + ((size_t)bh * S_LEN + i0) * HD;
  const u16* kp = k + (size_t)bh * S_LEN * HD;
  const u16* vp = vt + (size_t)bh * HD * S_LEN;

  // stage Q async (8KB = 8 segs; wave w does segs {w, w+4})
#pragma unroll
  for (int u = 0; u < 2; u++) {
    int seg = u * 4 + w;
    int chunk = seg * 64 + lane;
    gl_lds16(&qp[(size_t)(chunk >> 3) * HD + ((chunk & 7) << 3)], &Qs[seg * 512]);
  }

  int cl = i0 - WIN; if (cl < 0) cl = 0;
  int chi = i0 + 63 + WIN; if (chi > S_LEN - 1) chi = S_LEN - 1;
  int nch = (chi - cl + 64) >> 6;
  int tlo = (cl + 255) >> 8;
  int thi0 = (chi >> 8) + 1;
  int ng = tlo + 8 - thi0;                 // globals outside window

  float m_i[4], l_i[4];
  f32x4 o[4];
#pragma unroll
  for (int r = 0; r < 4; r++) { m_i[r] = -INFINITY; l_i[r] = 0.f; }
#pragma unroll
  for (int tj = 0; tj < 4; tj++) o[tj] = (f32x4){0.f, 0.f, 0.f, 0.f};

  for (int ch = 0; ch <= nch; ch++) {
    bool is_g = (ch == nch);
    int c0 = cl + (ch << 6);
    __syncthreads();                       // prev chunk's reads done
    if (!is_g) {
#pragma unroll
      for (int u = 0; u < 2; u++) {
        int seg = u * 4 + w;
        int chunk = seg * 64 + lane;
        int rr = chunk >> 3, cc8 = (chunk & 7) << 3;
        gl_lds16(&kp[(size_t)(c0 + rr) * HD + cc8], &Ks[seg * 512]);
        gl_lds16(&vp[(size_t)rr * S_LEN + c0 + cc8], &Vs[seg * 512]);
      }
    } else {
      if (w == 0) {                        // K globals: 8 rows, one async inst
        int rr = lane >> 3;
        int grow = (rr < tlo) ? (rr << 8) : ((thi0 + rr - tlo) << 8);
        if (rr >= ng) grow = 0;
        gl_lds16(&kp[(size_t)grow * HD + ((lane & 7) << 3)], &Ks[0]);
      }
      // V globals: Vs[d][cg], cg<ng; tiny scatter (stale cols get p=0)
      for (int e = tid; e < 64 * 8; e += 256) {
        int d = e & 63, cg = e >> 6;
        if (cg < ng) {
          int gs = (cg < tlo) ? (cg << 8) : ((thi0 + cg - tlo) << 8);
          Vs[d * 64 + cg] = vp[(size_t)d * S_LEN + gs];
        }
      }
    }
    __syncthreads();

    // QK^T: S rows band [16w,16w+16), cols 0..63
    f32x4 s[4];
#pragma unroll
    for (int tj = 0; tj < 4; tj++) s[tj] = (f32x4){0.f, 0.f, 0.f, 0.f};
#pragma unroll
    for (int k2 = 0; k2 < 64; k2 += 32) {
      bf16x8 a = *(const bf16x8*)&Qs[(w * 16 + lm) * 64 + k2 + quad * 8];
#pragma unroll
      for (int tj = 0; tj < 4; tj++) {
        bf16x8 bfr = *(const bf16x8*)&Ks[(tj * 16 + lm) * 64 + k2 + quad * 8];
        s[tj] = __builtin_amdgcn_mfma_f32_16x16x32_bf16(a, bfr, s[tj], 0, 0, 0);
      }
    }
    // mask invalid cols (lane's col = tj*16+lm, all 4 regs share it)
#pragma unroll
    for (int tj = 0; tj < 4; tj++) {
      int cidx = tj * 16 + lm;
      bool inval = is_g ? (cidx >= ng) : (c0 + cidx > chi);
      if (inval) {
        s[tj][0] = -INFINITY; s[tj][1] = -INFINITY;
        s[tj][2] = -INFINITY; s[tj][3] = -INFINITY;
      }
    }
    // online softmax: row r lives on 16 lanes (lm) x 4 regs (tj)
#pragma unroll
    for (int r = 0; r < 4; r++) {
      float mx = fmaxf(fmaxf(s[0][r], s[1][r]), fmaxf(s[2][r], s[3][r]));
      mx = fmaxf(mx, __shfl_xor(mx, 1)); mx = fmaxf(mx, __shfl_xor(mx, 2));
      mx = fmaxf(mx, __shfl_xor(mx, 4)); mx = fmaxf(mx, __shfl_xor(mx, 8));
      float mnew = fmaxf(m_i[r], mx);
      float al = __expf(m_i[r] - mnew);
      float rs = 0.f;
#pragma unroll
      for (int tj = 0; tj < 4; tj++) {
        float p = __expf(s[tj][r] - mnew);
        s[tj][r] = p; rs += p;
      }
      rs += __shfl_xor(rs, 1); rs += __shfl_xor(rs, 2);
      rs += __shfl_xor(rs, 4); rs += __shfl_xor(rs, 8);
      l_i[r] = l_i[r] * al + rs;
      m_i[r] = mnew;
      o[0][r] *= al; o[1][r] *= al; o[2][r] *= al; o[3][r] *= al;
    }
    // P -> LDS (own band only; same-wave write->read, no barrier needed)
#pragma unroll
    for (int tj = 0; tj < 4; tj++)
#pragma unroll
      for (int r = 0; r < 4; r++)
        Ps[(w * 16 + quad * 4 + r) * PST + tj * 16 + lm] = f2bf(s[tj][r]);
    // PV: O[q][d] += P[q][c] * V^T[d][c]
#pragma unroll
    for (int k2 = 0; k2 < 64; k2 += 32) {
      bf16x8 a = *(const bf16x8*)&Ps[(w * 16 + lm) * PST + k2 + quad * 8];
#pragma unroll
      for (int tj = 0; tj < 4; tj++) {
        bf16x8 bfr = *(const bf16x8*)&Vs[(tj * 16 + lm) * 64 + k2 + quad * 8];
        o[tj] = __builtin_amdgcn_mfma_f32_16x16x32_bf16(a, bfr, o[tj], 0, 0, 0);
      }
    }
  }

  // epilogue -> y (S,B,E) bf16
#pragma unroll
  for (int r = 0; r < 4; r++) {
    int sg = i0 + w * 16 + quad * 4 + r;
    float inv = 1.f / l_i[r];
#pragma unroll
    for (int tj = 0; tj < 4; tj++) {
      int d = tj * 16 + lm;
      yb[((size_t)sg * B_SZ + b) * E_DIM + h * HD + d] = f2bf(o[tj][r] * inv);
    }
  }
}

// ---------------------------------------------------------------------------
// residual add + LayerNorm; optional bf16 secondary output
// ---------------------------------------------------------------------------
__global__ __launch_bounds__(256) void add_ln_kernel(
    const float* __restrict__ a, const float* __restrict__ r,
    const float* __restrict__ g, const float* __restrict__ be,
    float* __restrict__ out, u16* __restrict__ outb) {
  int wave = threadIdx.x >> 6;
  int lane = threadIdx.x & 63;
  int row = blockIdx.x * 4 + wave;
  const float* ar = a + (size_t)row * E_DIM;
  const float* rr = r + (size_t)row * E_DIM;
  float vals[8];
  float s = 0.f;
#pragma unroll
  for (int t = 0; t < 8; t++) {
    vals[t] = ar[t * 64 + lane] + rr[t * 64 + lane];
    s += vals[t];
  }
#pragma unroll
  for (int o = 32; o >= 1; o >>= 1) s += __shfl_xor(s, o, 64);
  float mu = s * (1.f / E_DIM);
  float vs = 0.f;
#pragma unroll
  for (int t = 0; t < 8; t++) { float d = vals[t] - mu; vs += d * d; }
#pragma unroll
  for (int o = 32; o >= 1; o >>= 1) vs += __shfl_xor(vs, o, 64);
  float inv = rsqrtf(vs * (1.f / E_DIM) + 1e-5f);
  float* orow = out + (size_t)row * E_DIM;
  u16* obrow = outb ? outb + (size_t)row * E_DIM : nullptr;
#pragma unroll
  for (int t = 0; t < 8; t++) {
    int e = t * 64 + lane;
    float val = (vals[t] - mu) * inv * g[e] + be[e];
    orow[e] = val;
    if (obrow) obrow[e] = f2bf(val);
  }
}

// ---------------------------------------------------------------------------
// launch
// ---------------------------------------------------------------------------
extern "C" void kernel_launch(void* const* d_in, const int* in_sizes, int n_in,
                              void* d_out, int out_size, void* d_ws, size_t ws_size,
                              hipStream_t stream) {
  const float* x     = (const float*)d_in[0];
  const float* pos   = (const float*)d_in[1];
  const float* in_w  = (const float*)d_in[2];
  const float* in_b  = (const float*)d_in[3];
  const float* out_w = (const float*)d_in[4];
  const float* out_b = (const float*)d_in[5];
  const float* w1    = (const float*)d_in[6];
  const float* b1    = (const float*)d_in[7];
  const float* w2    = (const float*)d_in[8];
  const float* b2    = (const float*)d_in[9];
  const float* g1    = (const float*)d_in[10];
  const float* be1   = (const float*)d_in[11];
  const float* g2    = (const float*)d_in[12];
  const float* be2   = (const float*)d_in[13];
  float* out = (float*)d_out;

  // workspace (80 MB peak, byte offsets):
  //   0    xp fp32 16MB (-> x1 in-place)
  //   16M  xpb bf16 8MB (-> x1b)
  //   24M  qb bf16 8MB   \
  //   32M  kb bf16 8MB    } -> ff1b bf16 32MB (24M..56M) after attention
  //   40M  vtb bf16 8MB  /   (vtb overrun pad: ybf follows)
  //   48M  ybf bf16 8MB
  //   56M  aprj fp32 16MB -> ff2
  //   72M  bf16 weights: inwb 1.5M | outwb @74M 0.5M | w1b @76M 2M | w2b @78M
  char* base = (char*)d_ws;
  float* xp    = (float*)(base);
  u16*   xpb   = (u16*)(base + ((size_t)16 << 20));
  u16*   qb    = (u16*)(base + ((size_t)24 << 20));
  u16*   kb    = (u16*)(base + ((size_t)32 << 20));
  u16*   vtb   = (u16*)(base + ((size_t)40 << 20));
  u16*   ybf   = (u16*)(base + ((size_t)48 << 20));
  float* aprj  = (float*)(base + ((size_t)56 << 20));
  u16*   inwb  = (u16*)(base + ((size_t)72 << 20));
  u16*   outwb = (u16*)(base + ((size_t)74 << 20));
  u16*   w1b   = (u16*)(base + ((size_t)76 << 20));
  u16*   w2b   = (u16*)(base + ((size_t)78 << 20));
  float* x1    = xp;
  u16*   x1b   = xpb;
  u16*   ff1b  = qb;
  float* ff2   = aprj;

  wcast_kernel<<<3072, 256, 0, stream>>>(in_w, out_w, w1, w2, inwb, outwb, w1b, w2b);
  add_pos_kernel<<<4096, 256, 0, stream>>>(x, pos, xp, xpb);
  mfma_gemm<<<dim3(64, 12), 256, 0, stream>>>(xpb, inwb, in_b, nullptr, nullptr,
                                              NROWS, 1536, 512, 2, qb, kb, vtb);
  attn_mfma_kernel<<<dim3(32, 32), 256, 0, stream>>>(qb, kb, vtb, ybf);
  mfma_gemm<<<dim3(64, 4), 256, 0, stream>>>(ybf, outwb, out_b, aprj, nullptr,
                                             NROWS, 512, 512, 0, nullptr, nullptr, nullptr);
  add_ln_kernel<<<2048, 256, 0, stream>>>(xp, aprj, g1, be1, x1, x1b);
  mfma_gemm<<<dim3(64, 16), 256, 0, stream>>>(x1b, w1b, b1, nullptr, ff1b,
                                              NROWS, 2048, 512, 1, nullptr, nullptr, nullptr);
  mfma_gemm<<<dim3(64, 4), 256, 0, stream>>>(ff1b, w2b, b2, ff2, nullptr,
                                             NROWS, 512, 2048, 0, nullptr, nullptr, nullptr);
  add_ln_kernel<<<2048, 256, 0, stream>>>(x1, ff2, g2, be2, out, nullptr);
}

// Round 4
// 302.172 us; speedup vs baseline: 4.7360x; 1.0288x over previous
//
#include <hip/hip_runtime.h>
#include <hip/hip_bf16.h>
#include <math.h>

#define S_LEN 2048
#define B_SZ  4
#define E_DIM 512
#define H_NUM 8
#define HD    64
#define FF_DIM 2048
#define NROWS 8192
#define WIN   128

typedef unsigned short u16;
typedef __bf16 bf16x8 __attribute__((ext_vector_type(8)));
typedef float  f32x4  __attribute__((ext_vector_type(4)));

// fp32 -> bf16 round-to-nearest-even
__device__ __forceinline__ u16 f2bf(float f) {
  union { float f; unsigned u; } v; v.f = f;
  unsigned u = v.u;
  return (u16)((u + 0x7fffu + ((u >> 16) & 1u)) >> 16);
}

// async global->LDS, 16B per lane; LDS dest = wave-uniform base + lane*16
__device__ __forceinline__ void gl_lds16(const u16* gp, u16* lp) {
  __builtin_amdgcn_global_load_lds(
      (const __attribute__((address_space(1))) unsigned int*)gp,
      (__attribute__((address_space(3))) unsigned int*)lp, 16, 0, 0);
}

// ---------------------------------------------------------------------------
// weight cast: 4 fp32 matrices -> bf16
// ---------------------------------------------------------------------------
__global__ __launch_bounds__(256) void wcast_kernel(
    const float* __restrict__ s0, const float* __restrict__ s1,
    const float* __restrict__ s2, const float* __restrict__ s3,
    u16* __restrict__ d0, u16* __restrict__ d1,
    u16* __restrict__ d2, u16* __restrict__ d3) {
  const int n0 = 196608, n1 = 65536, n2 = 262144;
  int i = blockIdx.x * blockDim.x + threadIdx.x;
  const float4* sp; ushort4* dp; int off;
  if (i < n0)                { sp = (const float4*)s0; dp = (ushort4*)d0; off = i; }
  else if (i < n0 + n1)      { sp = (const float4*)s1; dp = (ushort4*)d1; off = i - n0; }
  else if (i < n0 + n1 + n2) { sp = (const float4*)s2; dp = (ushort4*)d2; off = i - n0 - n1; }
  else                       { sp = (const float4*)s3; dp = (ushort4*)d3; off = i - n0 - n1 - n2; }
  float4 v = sp[off];
  ushort4 o; o.x = f2bf(v.x); o.y = f2bf(v.y); o.z = f2bf(v.z); o.w = f2bf(v.w);
  dp[off] = o;
}

// ---------------------------------------------------------------------------
// x + pos (pos[:, :B, :] broadcast over seq) -> fp32 + bf16 copies
// ---------------------------------------------------------------------------
__global__ __launch_bounds__(256) void add_pos_kernel(
    const float* __restrict__ x, const float* __restrict__ pos,
    float* __restrict__ xp, u16* __restrict__ xpb) {
  int idx = blockIdx.x * blockDim.x + threadIdx.x;
  float4 xv = ((const float4*)x)[idx];
  float4 pv = ((const float4*)pos)[idx & 511];
  float4 o;
  o.x = xv.x + pv.x; o.y = xv.y + pv.y; o.z = xv.z + pv.z; o.w = xv.w + pv.w;
  ((float4*)xp)[idx] = o;
  ushort4 ob; ob.x = f2bf(o.x); ob.y = f2bf(o.y); ob.z = f2bf(o.z); ob.w = f2bf(o.w);
  ((ushort4*)xpb)[idx] = ob;
}

// ---------------------------------------------------------------------------
// bf16 MFMA GEMM: 128x128 tile, BK=64, global_load_lds width=16, XOR-swizzled
// LDS (chunk g of row r stored at chunk g^(r&7); breaks 128B-stride 16-way
// bank conflicts -> 2-way free).
// mode 0: fp32 out | mode 1: relu -> bf16 out | mode 2: scatter q(scaled)/k/v
// ---------------------------------------------------------------------------
#define GBK 64

__global__ __launch_bounds__(256) void mfma_gemm(
    const u16* __restrict__ A, const u16* __restrict__ W,
    const float* __restrict__ bias, float* __restrict__ outf,
    u16* __restrict__ outb, int M, int N, int K, int mode,
    u16* __restrict__ qb, u16* __restrict__ kb, u16* __restrict__ vb) {
  __shared__ u16 As[128 * GBK];
  __shared__ u16 Bs[128 * GBK];
  int tid = threadIdx.x;
  int lane = tid & 63;
  int w = tid >> 6;
  int m0 = blockIdx.x * 128;
  int j0 = blockIdx.y * 128;
  int wrow = (w >> 1) * 64;
  int wcol = (w & 1) * 64;
  int lm = lane & 15;
  int kq = lane >> 4;
  int sw = lm & 7;                // read-side swizzle key (= row & 7)
  int r8 = lane >> 3;             // staging: row-within-seg (= row & 7)
  int csrc = ((lane & 7) ^ r8) << 3;  // staging source col (u16), swizzled

  f32x4 acc[4][4];
#pragma unroll
  for (int i = 0; i < 4; i++)
#pragma unroll
    for (int j = 0; j < 4; j++) acc[i][j] = (f32x4){0.f, 0.f, 0.f, 0.f};

  const u16* Ab = A + (size_t)m0 * K;
  const u16* Wb = W + (size_t)j0 * K;

  for (int kt = 0; kt < K; kt += GBK) {
    __syncthreads();
#pragma unroll
    for (int u = 0; u < 4; u++) {          // 16 segs x 1KB per array
      int seg = u * 4 + w;
      int r = seg * 8 + r8;
      gl_lds16(&Ab[(size_t)r * K + kt + csrc], &As[seg * 512]);
      gl_lds16(&Wb[(size_t)r * K + kt + csrc], &Bs[seg * 512]);
    }
    __syncthreads();
#pragma unroll
    for (int k2 = 0; k2 < GBK; k2 += 32) {
      int cb = (k2 >> 3) + kq;
      bf16x8 af[4], bfr[4];
#pragma unroll
      for (int t = 0; t < 4; t++) {
        af[t]  = *(const bf16x8*)&As[(wrow + t * 16 + lm) * GBK + ((cb ^ sw) << 3)];
        bfr[t] = *(const bf16x8*)&Bs[(wcol + t * 16 + lm) * GBK + ((cb ^ sw) << 3)];
      }
#pragma unroll
      for (int ti = 0; ti < 4; ti++)
#pragma unroll
        for (int tj = 0; tj < 4; tj++)
          acc[ti][tj] = __builtin_amdgcn_mfma_f32_16x16x32_bf16(
              af[ti], bfr[tj], acc[ti][tj], 0, 0, 0);
    }
  }

  // C/D layout: col=lane&15, row=(lane>>4)*4+reg
#pragma unroll
  for (int tj = 0; tj < 4; tj++) {
    int n = j0 + wcol + tj * 16 + lm;
    float bv = bias[n];
#pragma unroll
    for (int ti = 0; ti < 4; ti++) {
#pragma unroll
      for (int r = 0; r < 4; r++) {
        int m = m0 + wrow + ti * 16 + kq * 4 + r;
        float val = acc[ti][tj][r] + bv;
        if (mode == 0) {
          outf[(size_t)m * N + n] = val;
        } else if (mode == 1) {
          outb[(size_t)m * N + n] = f2bf(fmaxf(val, 0.f));
        } else {
          int which = n >> 9, e = n & 511, h = e >> 6, d = e & 63;
          int s = m >> 2, b = m & 3;
          int bh = b * H_NUM + h;
          if (which == 0)       // q pre-scaled by 1/sqrt(hd)
            qb[((size_t)bh * S_LEN + s) * HD + d] = f2bf(val * 0.125f);
          else if (which == 1)
            kb[((size_t)bh * S_LEN + s) * HD + d] = f2bf(val);
          else                  // v contiguous (b,h,s,d); attn transposes in LDS
            vb[((size_t)bh * S_LEN + s) * HD + d] = f2bf(val);
        }
      }
    }
  }
}

// ---------------------------------------------------------------------------
// MFMA attention: block = (64 queries) x (b,h); wave w owns query rows
// [16w,16w+16). Qs/Ks staged via global_load_lds with the same XOR swizzle;
// Vs[d][c] built by in-LDS transpose of contiguous v rows (swizzled store).
// ---------------------------------------------------------------------------
#define PST 72   // Ps row stride (u16): breaks pow2 banks

__global__ __launch_bounds__(256) void attn_mfma_kernel(
    const u16* __restrict__ q, const u16* __restrict__ k,
    const u16* __restrict__ v, u16* __restrict__ yb) {
  __shared__ u16 Qs[64 * 64];   // [q][d] swizzled
  __shared__ u16 Ks[64 * 64];   // [c][d] swizzled
  __shared__ u16 Vs[64 * 64];   // [d][c] swizzled
  __shared__ u16 Ps[64 * PST];  // [q][c] bf16, pad-stride
  int tid = threadIdx.x, lane = tid & 63, w = tid >> 6;
  int quad = lane >> 4, lm = lane & 15;
  int sw = lm & 7;
  int r8 = lane >> 3;
  int csrc = ((lane & 7) ^ r8) << 3;
  int i0 = blockIdx.x * 64, bh = blockIdx.y;
  int b = bh >> 3, h = bh & 7;
  const u16* qp = q + ((size_t)bh * S_LEN + i0) * HD;
  const u16* kp = k + (size_t)bh * S_LEN * HD;
  const u16* vp = v + (size_t)bh * S_LEN * HD;

  // stage Q async, swizzled (8 segs; wave w does segs {w, w+4})
#pragma unroll
  for (int u = 0; u < 2; u++) {
    int seg = u * 4 + w;
    int r = seg * 8 + r8;
    gl_lds16(&qp[(size_t)r * HD + csrc], &Qs[seg * 512]);
  }

  int cl = i0 - WIN; if (cl < 0) cl = 0;
  int chi = i0 + 63 + WIN; if (chi > S_LEN - 1) chi = S_LEN - 1;
  int nch = (chi - cl + 64) >> 6;
  int tlo = (cl + 255) >> 8;
  int thi0 = (chi >> 8) + 1;
  int ng = tlo + 8 - thi0;                 // globals outside window

  float m_i[4], l_i[4];
  f32x4 o[4];
#pragma unroll
  for (int r = 0; r < 4; r++) { m_i[r] = -INFINITY; l_i[r] = 0.f; }
#pragma unroll
  for (int tj = 0; tj < 4; tj++) o[tj] = (f32x4){0.f, 0.f, 0.f, 0.f};

  for (int ch = 0; ch <= nch; ch++) {
    bool is_g = (ch == nch);
    int c0 = cl + (ch << 6);
    __syncthreads();                       // prev chunk's reads done
    if (!is_g) {
#pragma unroll
      for (int u = 0; u < 2; u++) {        // K: async swizzled
        int seg = u * 4 + w;
        int r = seg * 8 + r8;
        gl_lds16(&kp[(size_t)(c0 + r) * HD + csrc], &Ks[seg * 512]);
      }
      // V: coalesced row loads, transposed+swizzled LDS store (zero-fill OOB)
#pragma unroll
      for (int it = 0; it < 4; it++) {
        int flat = it * 256 + tid;         // 0..1023
        int c = flat >> 4;                 // key col 0..63
        int d0 = (flat & 15) << 2;
        ushort4 vv = make_ushort4(0, 0, 0, 0);
        int src = c0 + c;
        if (src <= chi) vv = *(const ushort4*)&vp[(size_t)src * HD + d0];
        u16 arr[4] = {vv.x, vv.y, vv.z, vv.w};
#pragma unroll
        for (int jd = 0; jd < 4; jd++) {
          int d = d0 + jd;
          Vs[d * 64 + ((((c >> 3) ^ (d & 7)) << 3) | (c & 7))] = arr[jd];
        }
      }
    } else {
      if (w == 0) {                        // K globals: 8 rows, one async inst
        int rr = lane >> 3;
        int grow = (rr < tlo) ? (rr << 8) : ((thi0 + rr - tlo) << 8);
        if (rr >= ng) grow = 0;
        gl_lds16(&kp[(size_t)grow * HD + (((lane & 7) ^ rr) << 3)], &Ks[0]);
      }
      // V globals: Vs[d][cg], cg<ng (chunk 0 -> swizzle key d&7)
      for (int e = tid; e < 64 * 8; e += 256) {
        int d = e & 63, cg = e >> 6;
        if (cg < ng) {
          int gs = (cg < tlo) ? (cg << 8) : ((thi0 + cg - tlo) << 8);
          Vs[d * 64 + ((d & 7) << 3) + cg] = vp[(size_t)gs * HD + d];
        }
      }
    }
    __syncthreads();

    // QK^T: S rows band [16w,16w+16), cols 0..63
    f32x4 s[4];
#pragma unroll
    for (int tj = 0; tj < 4; tj++) s[tj] = (f32x4){0.f, 0.f, 0.f, 0.f};
#pragma unroll
    for (int k2 = 0; k2 < 64; k2 += 32) {
      int cb = (k2 >> 3) + quad;
      bf16x8 a = *(const bf16x8*)&Qs[(w * 16 + lm) * 64 + ((cb ^ sw) << 3)];
#pragma unroll
      for (int tj = 0; tj < 4; tj++) {
        bf16x8 bfr = *(const bf16x8*)&Ks[(tj * 16 + lm) * 64 + ((cb ^ sw) << 3)];
        s[tj] = __builtin_amdgcn_mfma_f32_16x16x32_bf16(a, bfr, s[tj], 0, 0, 0);
      }
    }
    // mask invalid cols (lane's col = tj*16+lm, all 4 regs share it)
#pragma unroll
    for (int tj = 0; tj < 4; tj++) {
      int cidx = tj * 16 + lm;
      bool inval = is_g ? (cidx >= ng) : (c0 + cidx > chi);
      if (inval) {
        s[tj][0] = -INFINITY; s[tj][1] = -INFINITY;
        s[tj][2] = -INFINITY; s[tj][3] = -INFINITY;
      }
    }
    // online softmax: row r lives on 16 lanes (lm) x 4 regs (tj)
#pragma unroll
    for (int r = 0; r < 4; r++) {
      float mx = fmaxf(fmaxf(s[0][r], s[1][r]), fmaxf(s[2][r], s[3][r]));
      mx = fmaxf(mx, __shfl_xor(mx, 1)); mx = fmaxf(mx, __shfl_xor(mx, 2));
      mx = fmaxf(mx, __shfl_xor(mx, 4)); mx = fmaxf(mx, __shfl_xor(mx, 8));
      float mnew = fmaxf(m_i[r], mx);
      float al = __expf(m_i[r] - mnew);
      float rs = 0.f;
#pragma unroll
      for (int tj = 0; tj < 4; tj++) {
        float p = __expf(s[tj][r] - mnew);
        s[tj][r] = p; rs += p;
      }
      rs += __shfl_xor(rs, 1); rs += __shfl_xor(rs, 2);
      rs += __shfl_xor(rs, 4); rs += __shfl_xor(rs, 8);
      l_i[r] = l_i[r] * al + rs;
      m_i[r] = mnew;
      o[0][r] *= al; o[1][r] *= al; o[2][r] *= al; o[3][r] *= al;
    }
    // P -> LDS (own band only; same-wave write->read)
#pragma unroll
    for (int tj = 0; tj < 4; tj++)
#pragma unroll
      for (int r = 0; r < 4; r++)
        Ps[(w * 16 + quad * 4 + r) * PST + tj * 16 + lm] = f2bf(s[tj][r]);
    // PV: O[q][d] += P[q][c] * Vs[d][c]
#pragma unroll
    for (int k2 = 0; k2 < 64; k2 += 32) {
      int cb = (k2 >> 3) + quad;
      bf16x8 a = *(const bf16x8*)&Ps[(w * 16 + lm) * PST + k2 + quad * 8];
#pragma unroll
      for (int tj = 0; tj < 4; tj++) {
        bf16x8 bfr = *(const bf16x8*)&Vs[(tj * 16 + lm) * 64 + ((cb ^ sw) << 3)];
        o[tj] = __builtin_amdgcn_mfma_f32_16x16x32_bf16(a, bfr, o[tj], 0, 0, 0);
      }
    }
  }

  // epilogue -> y (S,B,E) bf16
#pragma unroll
  for (int r = 0; r < 4; r++) {
    int sg = i0 + w * 16 + quad * 4 + r;
    float inv = 1.f / l_i[r];
#pragma unroll
    for (int tj = 0; tj < 4; tj++) {
      int d = tj * 16 + lm;
      yb[((size_t)sg * B_SZ + b) * E_DIM + h * HD + d] = f2bf(o[tj][r] * inv);
    }
  }
}

// ---------------------------------------------------------------------------
// residual add + LayerNorm; optional bf16 secondary output
// ---------------------------------------------------------------------------
__global__ __launch_bounds__(256) void add_ln_kernel(
    const float* __restrict__ a, const float* __restrict__ r,
    const float* __restrict__ g, const float* __restrict__ be,
    float* __restrict__ out, u16* __restrict__ outb) {
  int wave = threadIdx.x >> 6;
  int lane = threadIdx.x & 63;
  int row = blockIdx.x * 4 + wave;
  const float* ar = a + (size_t)row * E_DIM;
  const float* rr = r + (size_t)row * E_DIM;
  float vals[8];
  float s = 0.f;
#pragma unroll
  for (int t = 0; t < 8; t++) {
    vals[t] = ar[t * 64 + lane] + rr[t * 64 + lane];
    s += vals[t];
  }
#pragma unroll
  for (int o = 32; o >= 1; o >>= 1) s += __shfl_xor(s, o, 64);
  float mu = s * (1.f / E_DIM);
  float vs = 0.f;
#pragma unroll
  for (int t = 0; t < 8; t++) { float d = vals[t] - mu; vs += d * d; }
#pragma unroll
  for (int o = 32; o >= 1; o >>= 1) vs += __shfl_xor(vs, o, 64);
  float inv = rsqrtf(vs * (1.f / E_DIM) + 1e-5f);
  float* orow = out + (size_t)row * E_DIM;
  u16* obrow = outb ? outb + (size_t)row * E_DIM : nullptr;
#pragma unroll
  for (int t = 0; t < 8; t++) {
    int e = t * 64 + lane;
    float val = (vals[t] - mu) * inv * g[e] + be[e];
    orow[e] = val;
    if (obrow) obrow[e] = f2bf(val);
  }
}

// ---------------------------------------------------------------------------
// launch
// ---------------------------------------------------------------------------
extern "C" void kernel_launch(void* const* d_in, const int* in_sizes, int n_in,
                              void* d_out, int out_size, void* d_ws, size_t ws_size,
                              hipStream_t stream) {
  const float* x     = (const float*)d_in[0];
  const float* pos   = (const float*)d_in[1];
  const float* in_w  = (const float*)d_in[2];
  const float* in_b  = (const float*)d_in[3];
  const float* out_w = (const float*)d_in[4];
  const float* out_b = (const float*)d_in[5];
  const float* w1    = (const float*)d_in[6];
  const float* b1    = (const float*)d_in[7];
  const float* w2    = (const float*)d_in[8];
  const float* b2    = (const float*)d_in[9];
  const float* g1    = (const float*)d_in[10];
  const float* be1   = (const float*)d_in[11];
  const float* g2    = (const float*)d_in[12];
  const float* be2   = (const float*)d_in[13];
  float* out = (float*)d_out;

  // workspace (80 MB peak): see R3; vb replaces vtb (now (b,h,s,d))
  char* base = (char*)d_ws;
  float* xp    = (float*)(base);
  u16*   xpb   = (u16*)(base + ((size_t)16 << 20));
  u16*   qb    = (u16*)(base + ((size_t)24 << 20));
  u16*   kb    = (u16*)(base + ((size_t)32 << 20));
  u16*   vb    = (u16*)(base + ((size_t)40 << 20));
  u16*   ybf   = (u16*)(base + ((size_t)48 << 20));
  float* aprj  = (float*)(base + ((size_t)56 << 20));
  u16*   inwb  = (u16*)(base + ((size_t)72 << 20));
  u16*   outwb = (u16*)(base + ((size_t)74 << 20));
  u16*   w1b   = (u16*)(base + ((size_t)76 << 20));
  u16*   w2b   = (u16*)(base + ((size_t)78 << 20));
  float* x1    = xp;
  u16*   x1b   = xpb;
  u16*   ff1b  = qb;      // 24M..56M (ybf already consumed when FF1 runs)
  float* ff2   = aprj;

  wcast_kernel<<<3072, 256, 0, stream>>>(in_w, out_w, w1, w2, inwb, outwb, w1b, w2b);
  add_pos_kernel<<<4096, 256, 0, stream>>>(x, pos, xp, xpb);
  mfma_gemm<<<dim3(64, 12), 256, 0, stream>>>(xpb, inwb, in_b, nullptr, nullptr,
                                              NROWS, 1536, 512, 2, qb, kb, vb);
  attn_mfma_kernel<<<dim3(32, 32), 256, 0, stream>>>(qb, kb, vb, ybf);
  mfma_gemm<<<dim3(64, 4), 256, 0, stream>>>(ybf, outwb, out_b, aprj, nullptr,
                                             NROWS, 512, 512, 0, nullptr, nullptr, nullptr);
  add_ln_kernel<<<2048, 256, 0, stream>>>(xp, aprj, g1, be1, x1, x1b);
  mfma_gemm<<<dim3(64, 16), 256, 0, stream>>>(x1b, w1b, b1, nullptr, ff1b,
                                              NROWS, 2048, 512, 1, nullptr, nullptr, nullptr);
  mfma_gemm<<<dim3(64, 4), 256, 0, stream>>>(ff1b, w2b, b2, ff2, nullptr,
                                             NROWS, 512, 2048, 0, nullptr, nullptr, nullptr);
  add_ln_kernel<<<2048, 256, 0, stream>>>(x1, ff2, g2, be2, out, nullptr);
}

// Round 5
// 283.577 us; speedup vs baseline: 5.0466x; 1.0656x over previous
//
#include <hip/hip_runtime.h>
#include <hip/hip_bf16.h>
#include <math.h>

#define S_LEN 2048
#define B_SZ  4
#define E_DIM 512
#define H_NUM 8
#define HD    64
#define FF_DIM 2048
#define NROWS 8192
#define WIN   128

typedef unsigned short u16;
typedef __bf16 bf16x8 __attribute__((ext_vector_type(8)));
typedef float  f32x4  __attribute__((ext_vector_type(4)));

// fp32 -> bf16 round-to-nearest-even
__device__ __forceinline__ u16 f2bf(float f) {
  union { float f; unsigned u; } v; v.f = f;
  unsigned u = v.u;
  return (u16)((u + 0x7fffu + ((u >> 16) & 1u)) >> 16);
}

// async global->LDS, 16B per lane; LDS dest = wave-uniform base + lane*16
__device__ __forceinline__ void gl_lds16(const u16* gp, u16* lp) {
  __builtin_amdgcn_global_load_lds(
      (const __attribute__((address_space(1))) unsigned int*)gp,
      (__attribute__((address_space(3))) unsigned int*)lp, 16, 0, 0);
}

// ---------------------------------------------------------------------------
// weight cast: 4 fp32 matrices -> bf16
// ---------------------------------------------------------------------------
__global__ __launch_bounds__(256) void wcast_kernel(
    const float* __restrict__ s0, const float* __restrict__ s1,
    const float* __restrict__ s2, const float* __restrict__ s3,
    u16* __restrict__ d0, u16* __restrict__ d1,
    u16* __restrict__ d2, u16* __restrict__ d3) {
  const int n0 = 196608, n1 = 65536, n2 = 262144;
  int i = blockIdx.x * blockDim.x + threadIdx.x;
  const float4* sp; ushort4* dp; int off;
  if (i < n0)                { sp = (const float4*)s0; dp = (ushort4*)d0; off = i; }
  else if (i < n0 + n1)      { sp = (const float4*)s1; dp = (ushort4*)d1; off = i - n0; }
  else if (i < n0 + n1 + n2) { sp = (const float4*)s2; dp = (ushort4*)d2; off = i - n0 - n1; }
  else                       { sp = (const float4*)s3; dp = (ushort4*)d3; off = i - n0 - n1 - n2; }
  float4 v = sp[off];
  ushort4 o; o.x = f2bf(v.x); o.y = f2bf(v.y); o.z = f2bf(v.z); o.w = f2bf(v.w);
  dp[off] = o;
}

// ---------------------------------------------------------------------------
// x + pos (pos[:, :B, :] broadcast over seq) -> fp32 + bf16 copies
// ---------------------------------------------------------------------------
__global__ __launch_bounds__(256) void add_pos_kernel(
    const float* __restrict__ x, const float* __restrict__ pos,
    float* __restrict__ xp, u16* __restrict__ xpb) {
  int idx = blockIdx.x * blockDim.x + threadIdx.x;
  float4 xv = ((const float4*)x)[idx];
  float4 pv = ((const float4*)pos)[idx & 511];
  float4 o;
  o.x = xv.x + pv.x; o.y = xv.y + pv.y; o.z = xv.z + pv.z; o.w = xv.w + pv.w;
  ((float4*)xp)[idx] = o;
  ushort4 ob; ob.x = f2bf(o.x); ob.y = f2bf(o.y); ob.z = f2bf(o.z); ob.w = f2bf(o.w);
  ((ushort4*)xpb)[idx] = ob;
}

// ---------------------------------------------------------------------------
// bf16 MFMA GEMM: 128xBN tile, BK=64, global_load_lds width=16, XOR-swizzled
// LDS, DOUBLE-BUFFERED: prefetch tile k+1 issued before computing tile k, so
// the single per-iter barrier drains loads that overlapped a compute phase.
// BN=128: 4 waves as 2x2 of 64x64. BN=64: 4 waves as 2x2 of 64x32 (2x grid
// for the N=512 GEMMs -> 2 blocks/CU).
// mode 0: fp32 out | mode 1: relu -> bf16 out | mode 2: scatter q(scaled)/k/v
// ---------------------------------------------------------------------------
#define GBK 64

template <int BN>
__global__ __launch_bounds__(256) void mfma_gemm(
    const u16* __restrict__ A, const u16* __restrict__ W,
    const float* __restrict__ bias, float* __restrict__ outf,
    u16* __restrict__ outb, int M, int N, int K, int mode,
    u16* __restrict__ qb, u16* __restrict__ kb, u16* __restrict__ vb) {
  constexpr int TJ = BN / 32;            // B frag tiles per wave
  constexpr int NBU = BN / 32;           // B staging rounds (segs/4)
  __shared__ u16 As[2][128 * GBK];
  __shared__ u16 Bs[2][BN * GBK];
  int tid = threadIdx.x;
  int lane = tid & 63;
  int w = tid >> 6;
  int m0 = blockIdx.x * 128;
  int j0 = blockIdx.y * BN;
  int wrow = (w >> 1) * 64;
  int wcol = (w & 1) * (BN / 2);
  int lm = lane & 15;
  int kq = lane >> 4;
  int sw = lm & 7;                       // read-side swizzle key (= row & 7)
  int r8 = lane >> 3;                    // staging row-within-seg
  int csrc = ((lane & 7) ^ r8) << 3;     // staging source col (u16), swizzled

  f32x4 acc[4][TJ];
#pragma unroll
  for (int i = 0; i < 4; i++)
#pragma unroll
    for (int j = 0; j < TJ; j++) acc[i][j] = (f32x4){0.f, 0.f, 0.f, 0.f};

  const u16* Ab = A + (size_t)m0 * K;
  const u16* Wb = W + (size_t)j0 * K;

  size_t soff[4];                        // per-wave staging offsets (row*K+col)
#pragma unroll
  for (int u = 0; u < 4; u++)
    soff[u] = (size_t)(u * 32 + w * 8 + r8) * K + csrc;

  auto stage = [&](int kt, int pb) {
#pragma unroll
    for (int u = 0; u < 4; u++)
      gl_lds16(&Ab[soff[u] + kt], &As[pb][(u * 4 + w) * 512]);
#pragma unroll
    for (int u = 0; u < NBU; u++)
      gl_lds16(&Wb[soff[u] + kt], &Bs[pb][(u * 4 + w) * 512]);
  };

  stage(0, 0);
  int pb = 0;
  for (int kt = 0; kt < K; kt += GBK) {
    __syncthreads();                     // drains vmcnt: buf[pb] ready; also
                                         // guarantees buf[pb^1] reads done
    if (kt + GBK < K) stage(kt + GBK, pb ^ 1);
#pragma unroll
    for (int k2 = 0; k2 < GBK; k2 += 32) {
      int cc = ((((k2 >> 3) + kq) ^ sw) << 3);
      bf16x8 af[4], bfr[TJ];
#pragma unroll
      for (int t = 0; t < 4; t++)
        af[t] = *(const bf16x8*)&As[pb][(wrow + t * 16 + lm) * GBK + cc];
#pragma unroll
      for (int tj = 0; tj < TJ; tj++)
        bfr[tj] = *(const bf16x8*)&Bs[pb][(wcol + tj * 16 + lm) * GBK + cc];
#pragma unroll
      for (int ti = 0; ti < 4; ti++)
#pragma unroll
        for (int tj = 0; tj < TJ; tj++)
          acc[ti][tj] = __builtin_amdgcn_mfma_f32_16x16x32_bf16(
              af[ti], bfr[tj], acc[ti][tj], 0, 0, 0);
    }
    pb ^= 1;
  }

  // C/D layout: col=lane&15, row=(lane>>4)*4+reg
#pragma unroll
  for (int tj = 0; tj < TJ; tj++) {
    int n = j0 + wcol + tj * 16 + lm;
    float bv = bias[n];
#pragma unroll
    for (int ti = 0; ti < 4; ti++) {
#pragma unroll
      for (int r = 0; r < 4; r++) {
        int m = m0 + wrow + ti * 16 + kq * 4 + r;
        float val = acc[ti][tj][r] + bv;
        if (mode == 0) {
          outf[(size_t)m * N + n] = val;
        } else if (mode == 1) {
          outb[(size_t)m * N + n] = f2bf(fmaxf(val, 0.f));
        } else {
          int which = n >> 9, e = n & 511, h = e >> 6, d = e & 63;
          int s = m >> 2, b = m & 3;
          int bh = b * H_NUM + h;
          if (which == 0)       // q pre-scaled by 1/sqrt(hd)
            qb[((size_t)bh * S_LEN + s) * HD + d] = f2bf(val * 0.125f);
          else if (which == 1)
            kb[((size_t)bh * S_LEN + s) * HD + d] = f2bf(val);
          else                  // v contiguous (b,h,s,d); attn transposes in LDS
            vb[((size_t)bh * S_LEN + s) * HD + d] = f2bf(val);
        }
      }
    }
  }
}

// ---------------------------------------------------------------------------
// MFMA attention (unchanged from R4): block = 64 queries x (b,h).
// ---------------------------------------------------------------------------
#define PST 72

__global__ __launch_bounds__(256) void attn_mfma_kernel(
    const u16* __restrict__ q, const u16* __restrict__ k,
    const u16* __restrict__ v, u16* __restrict__ yb) {
  __shared__ u16 Qs[64 * 64];   // [q][d] swizzled
  __shared__ u16 Ks[64 * 64];   // [c][d] swizzled
  __shared__ u16 Vs[64 * 64];   // [d][c] swizzled
  __shared__ u16 Ps[64 * PST];  // [q][c] bf16, pad-stride
  int tid = threadIdx.x, lane = tid & 63, w = tid >> 6;
  int quad = lane >> 4, lm = lane & 15;
  int sw = lm & 7;
  int r8 = lane >> 3;
  int csrc = ((lane & 7) ^ r8) << 3;
  int i0 = blockIdx.x * 64, bh = blockIdx.y;
  int b = bh >> 3, h = bh & 7;
  const u16* qp = q + ((size_t)bh * S_LEN + i0) * HD;
  const u16* kp = k + (size_t)bh * S_LEN * HD;
  const u16* vp = v + (size_t)bh * S_LEN * HD;

#pragma unroll
  for (int u = 0; u < 2; u++) {
    int seg = u * 4 + w;
    int r = seg * 8 + r8;
    gl_lds16(&qp[(size_t)r * HD + csrc], &Qs[seg * 512]);
  }

  int cl = i0 - WIN; if (cl < 0) cl = 0;
  int chi = i0 + 63 + WIN; if (chi > S_LEN - 1) chi = S_LEN - 1;
  int nch = (chi - cl + 64) >> 6;
  int tlo = (cl + 255) >> 8;
  int thi0 = (chi >> 8) + 1;
  int ng = tlo + 8 - thi0;

  float m_i[4], l_i[4];
  f32x4 o[4];
#pragma unroll
  for (int r = 0; r < 4; r++) { m_i[r] = -INFINITY; l_i[r] = 0.f; }
#pragma unroll
  for (int tj = 0; tj < 4; tj++) o[tj] = (f32x4){0.f, 0.f, 0.f, 0.f};

  for (int ch = 0; ch <= nch; ch++) {
    bool is_g = (ch == nch);
    int c0 = cl + (ch << 6);
    __syncthreads();
    if (!is_g) {
#pragma unroll
      for (int u = 0; u < 2; u++) {
        int seg = u * 4 + w;
        int r = seg * 8 + r8;
        gl_lds16(&kp[(size_t)(c0 + r) * HD + csrc], &Ks[seg * 512]);
      }
#pragma unroll
      for (int it = 0; it < 4; it++) {
        int flat = it * 256 + tid;
        int c = flat >> 4;
        int d0 = (flat & 15) << 2;
        ushort4 vv = make_ushort4(0, 0, 0, 0);
        int src = c0 + c;
        if (src <= chi) vv = *(const ushort4*)&vp[(size_t)src * HD + d0];
        u16 arr[4] = {vv.x, vv.y, vv.z, vv.w};
#pragma unroll
        for (int jd = 0; jd < 4; jd++) {
          int d = d0 + jd;
          Vs[d * 64 + ((((c >> 3) ^ (d & 7)) << 3) | (c & 7))] = arr[jd];
        }
      }
    } else {
      if (w == 0) {
        int rr = lane >> 3;
        int grow = (rr < tlo) ? (rr << 8) : ((thi0 + rr - tlo) << 8);
        if (rr >= ng) grow = 0;
        gl_lds16(&kp[(size_t)grow * HD + (((lane & 7) ^ rr) << 3)], &Ks[0]);
      }
      for (int e = tid; e < 64 * 8; e += 256) {
        int d = e & 63, cg = e >> 6;
        if (cg < ng) {
          int gs = (cg < tlo) ? (cg << 8) : ((thi0 + cg - tlo) << 8);
          Vs[d * 64 + ((d & 7) << 3) + cg] = vp[(size_t)gs * HD + d];
        }
      }
    }
    __syncthreads();

    f32x4 s[4];
#pragma unroll
    for (int tj = 0; tj < 4; tj++) s[tj] = (f32x4){0.f, 0.f, 0.f, 0.f};
#pragma unroll
    for (int k2 = 0; k2 < 64; k2 += 32) {
      int cb = (k2 >> 3) + quad;
      bf16x8 a = *(const bf16x8*)&Qs[(w * 16 + lm) * 64 + ((cb ^ sw) << 3)];
#pragma unroll
      for (int tj = 0; tj < 4; tj++) {
        bf16x8 bfr = *(const bf16x8*)&Ks[(tj * 16 + lm) * 64 + ((cb ^ sw) << 3)];
        s[tj] = __builtin_amdgcn_mfma_f32_16x16x32_bf16(a, bfr, s[tj], 0, 0, 0);
      }
    }
#pragma unroll
    for (int tj = 0; tj < 4; tj++) {
      int cidx = tj * 16 + lm;
      bool inval = is_g ? (cidx >= ng) : (c0 + cidx > chi);
      if (inval) {
        s[tj][0] = -INFINITY; s[tj][1] = -INFINITY;
        s[tj][2] = -INFINITY; s[tj][3] = -INFINITY;
      }
    }
#pragma unroll
    for (int r = 0; r < 4; r++) {
      float mx = fmaxf(fmaxf(s[0][r], s[1][r]), fmaxf(s[2][r], s[3][r]));
      mx = fmaxf(mx, __shfl_xor(mx, 1)); mx = fmaxf(mx, __shfl_xor(mx, 2));
      mx = fmaxf(mx, __shfl_xor(mx, 4)); mx = fmaxf(mx, __shfl_xor(mx, 8));
      float mnew = fmaxf(m_i[r], mx);
      float al = __expf(m_i[r] - mnew);
      float rs = 0.f;
#pragma unroll
      for (int tj = 0; tj < 4; tj++) {
        float p = __expf(s[tj][r] - mnew);
        s[tj][r] = p; rs += p;
      }
      rs += __shfl_xor(rs, 1); rs += __shfl_xor(rs, 2);
      rs += __shfl_xor(rs, 4); rs += __shfl_xor(rs, 8);
      l_i[r] = l_i[r] * al + rs;
      m_i[r] = mnew;
      o[0][r] *= al; o[1][r] *= al; o[2][r] *= al; o[3][r] *= al;
    }
#pragma unroll
    for (int tj = 0; tj < 4; tj++)
#pragma unroll
      for (int r = 0; r < 4; r++)
        Ps[(w * 16 + quad * 4 + r) * PST + tj * 16 + lm] = f2bf(s[tj][r]);
#pragma unroll
    for (int k2 = 0; k2 < 64; k2 += 32) {
      int cb = (k2 >> 3) + quad;
      bf16x8 a = *(const bf16x8*)&Ps[(w * 16 + lm) * PST + k2 + quad * 8];
#pragma unroll
      for (int tj = 0; tj < 4; tj++) {
        bf16x8 bfr = *(const bf16x8*)&Vs[(tj * 16 + lm) * 64 + ((cb ^ sw) << 3)];
        o[tj] = __builtin_amdgcn_mfma_f32_16x16x32_bf16(a, bfr, o[tj], 0, 0, 0);
      }
    }
  }

#pragma unroll
  for (int r = 0; r < 4; r++) {
    int sg = i0 + w * 16 + quad * 4 + r;
    float inv = 1.f / l_i[r];
#pragma unroll
    for (int tj = 0; tj < 4; tj++) {
      int d = tj * 16 + lm;
      yb[((size_t)sg * B_SZ + b) * E_DIM + h * HD + d] = f2bf(o[tj][r] * inv);
    }
  }
}

// ---------------------------------------------------------------------------
// residual add + LayerNorm; optional bf16 secondary output
// ---------------------------------------------------------------------------
__global__ __launch_bounds__(256) void add_ln_kernel(
    const float* __restrict__ a, const float* __restrict__ r,
    const float* __restrict__ g, const float* __restrict__ be,
    float* __restrict__ out, u16* __restrict__ outb) {
  int wave = threadIdx.x >> 6;
  int lane = threadIdx.x & 63;
  int row = blockIdx.x * 4 + wave;
  const float* ar = a + (size_t)row * E_DIM;
  const float* rr = r + (size_t)row * E_DIM;
  float vals[8];
  float s = 0.f;
#pragma unroll
  for (int t = 0; t < 8; t++) {
    vals[t] = ar[t * 64 + lane] + rr[t * 64 + lane];
    s += vals[t];
  }
#pragma unroll
  for (int o = 32; o >= 1; o >>= 1) s += __shfl_xor(s, o, 64);
  float mu = s * (1.f / E_DIM);
  float vs = 0.f;
#pragma unroll
  for (int t = 0; t < 8; t++) { float d = vals[t] - mu; vs += d * d; }
#pragma unroll
  for (int o = 32; o >= 1; o >>= 1) vs += __shfl_xor(vs, o, 64);
  float inv = rsqrtf(vs * (1.f / E_DIM) + 1e-5f);
  float* orow = out + (size_t)row * E_DIM;
  u16* obrow = outb ? outb + (size_t)row * E_DIM : nullptr;
#pragma unroll
  for (int t = 0; t < 8; t++) {
    int e = t * 64 + lane;
    float val = (vals[t] - mu) * inv * g[e] + be[e];
    orow[e] = val;
    if (obrow) obrow[e] = f2bf(val);
  }
}

// ---------------------------------------------------------------------------
// launch
// ---------------------------------------------------------------------------
extern "C" void kernel_launch(void* const* d_in, const int* in_sizes, int n_in,
                              void* d_out, int out_size, void* d_ws, size_t ws_size,
                              hipStream_t stream) {
  const float* x     = (const float*)d_in[0];
  const float* pos   = (const float*)d_in[1];
  const float* in_w  = (const float*)d_in[2];
  const float* in_b  = (const float*)d_in[3];
  const float* out_w = (const float*)d_in[4];
  const float* out_b = (const float*)d_in[5];
  const float* w1    = (const float*)d_in[6];
  const float* b1    = (const float*)d_in[7];
  const float* w2    = (const float*)d_in[8];
  const float* b2    = (const float*)d_in[9];
  const float* g1    = (const float*)d_in[10];
  const float* be1   = (const float*)d_in[11];
  const float* g2    = (const float*)d_in[12];
  const float* be2   = (const float*)d_in[13];
  float* out = (float*)d_out;

  char* base = (char*)d_ws;
  float* xp    = (float*)(base);
  u16*   xpb   = (u16*)(base + ((size_t)16 << 20));
  u16*   qb    = (u16*)(base + ((size_t)24 << 20));
  u16*   kb    = (u16*)(base + ((size_t)32 << 20));
  u16*   vb    = (u16*)(base + ((size_t)40 << 20));
  u16*   ybf   = (u16*)(base + ((size_t)48 << 20));
  float* aprj  = (float*)(base + ((size_t)56 << 20));
  u16*   inwb  = (u16*)(base + ((size_t)72 << 20));
  u16*   outwb = (u16*)(base + ((size_t)74 << 20));
  u16*   w1b   = (u16*)(base + ((size_t)76 << 20));
  u16*   w2b   = (u16*)(base + ((size_t)78 << 20));
  float* x1    = xp;
  u16*   x1b   = xpb;
  u16*   ff1b  = qb;      // 24M..56M
  float* ff2   = aprj;

  wcast_kernel<<<3072, 256, 0, stream>>>(in_w, out_w, w1, w2, inwb, outwb, w1b, w2b);
  add_pos_kernel<<<4096, 256, 0, stream>>>(x, pos, xp, xpb);
  mfma_gemm<128><<<dim3(64, 12), 256, 0, stream>>>(xpb, inwb, in_b, nullptr, nullptr,
                                                   NROWS, 1536, 512, 2, qb, kb, vb);
  attn_mfma_kernel<<<dim3(32, 32), 256, 0, stream>>>(qb, kb, vb, ybf);
  mfma_gemm<64><<<dim3(64, 8), 256, 0, stream>>>(ybf, outwb, out_b, aprj, nullptr,
                                                 NROWS, 512, 512, 0, nullptr, nullptr, nullptr);
  add_ln_kernel<<<2048, 256, 0, stream>>>(xp, aprj, g1, be1, x1, x1b);
  mfma_gemm<128><<<dim3(64, 16), 256, 0, stream>>>(x1b, w1b, b1, nullptr, ff1b,
                                                   NROWS, 2048, 512, 1, nullptr, nullptr, nullptr);
  mfma_gemm<64><<<dim3(64, 8), 256, 0, stream>>>(ff1b, w2b, b2, ff2, nullptr,
                                                 NROWS, 512, 2048, 0, nullptr, nullptr, nullptr);
  add_ln_kernel<<<2048, 256, 0, stream>>>(x1, ff2, g2, be2, out, nullptr);
}

// Round 6
// 267.697 us; speedup vs baseline: 5.3459x; 1.0593x over previous
//
#include <hip/hip_runtime.h>
#include <hip/hip_bf16.h>
#include <math.h>

#define S_LEN 2048
#define B_SZ  4
#define E_DIM 512
#define H_NUM 8
#define HD    64
#define FF_DIM 2048
#define NROWS 8192
#define WIN   128

typedef unsigned short u16;
typedef __bf16 bf16x8 __attribute__((ext_vector_type(8)));
typedef float  f32x4  __attribute__((ext_vector_type(4)));

// fp32 -> bf16 round-to-nearest-even
__device__ __forceinline__ u16 f2bf(float f) {
  union { float f; unsigned u; } v; v.f = f;
  unsigned u = v.u;
  return (u16)((u + 0x7fffu + ((u >> 16) & 1u)) >> 16);
}

// async global->LDS, 16B per lane; LDS dest = wave-uniform base + lane*16
__device__ __forceinline__ void gl_lds16(const u16* gp, u16* lp) {
  __builtin_amdgcn_global_load_lds(
      (const __attribute__((address_space(1))) unsigned int*)gp,
      (__attribute__((address_space(3))) unsigned int*)lp, 16, 0, 0);
}

// ---------------------------------------------------------------------------
// weight cast: 4 fp32 matrices -> bf16
// ---------------------------------------------------------------------------
__global__ __launch_bounds__(256) void wcast_kernel(
    const float* __restrict__ s0, const float* __restrict__ s1,
    const float* __restrict__ s2, const float* __restrict__ s3,
    u16* __restrict__ d0, u16* __restrict__ d1,
    u16* __restrict__ d2, u16* __restrict__ d3) {
  const int n0 = 196608, n1 = 65536, n2 = 262144;
  int i = blockIdx.x * blockDim.x + threadIdx.x;
  const float4* sp; ushort4* dp; int off;
  if (i < n0)                { sp = (const float4*)s0; dp = (ushort4*)d0; off = i; }
  else if (i < n0 + n1)      { sp = (const float4*)s1; dp = (ushort4*)d1; off = i - n0; }
  else if (i < n0 + n1 + n2) { sp = (const float4*)s2; dp = (ushort4*)d2; off = i - n0 - n1; }
  else                       { sp = (const float4*)s3; dp = (ushort4*)d3; off = i - n0 - n1 - n2; }
  float4 v = sp[off];
  ushort4 o; o.x = f2bf(v.x); o.y = f2bf(v.y); o.z = f2bf(v.z); o.w = f2bf(v.w);
  dp[off] = o;
}

// ---------------------------------------------------------------------------
// x + pos (pos[:, :B, :] broadcast over seq) -> fp32 + bf16 copies
// ---------------------------------------------------------------------------
__global__ __launch_bounds__(256) void add_pos_kernel(
    const float* __restrict__ x, const float* __restrict__ pos,
    float* __restrict__ xp, u16* __restrict__ xpb) {
  int idx = blockIdx.x * blockDim.x + threadIdx.x;
  float4 xv = ((const float4*)x)[idx];
  float4 pv = ((const float4*)pos)[idx & 511];
  float4 o;
  o.x = xv.x + pv.x; o.y = xv.y + pv.y; o.z = xv.z + pv.z; o.w = xv.w + pv.w;
  ((float4*)xp)[idx] = o;
  ushort4 ob; ob.x = f2bf(o.x); ob.y = f2bf(o.y); ob.z = f2bf(o.z); ob.w = f2bf(o.w);
  ((ushort4*)xpb)[idx] = ob;
}

// ---------------------------------------------------------------------------
// bf16 MFMA GEMM: 128xBN tile, BK=64, 512 threads (8 waves -> 16 waves/CU at
// 2 blocks/CU), global_load_lds width=16, XOR-swizzled LDS, double-buffered,
// XCD-aware block remap: all GY j-blocks of one m-tile land on one XCD so the
// A-tile stays in that XCD's L2 (per-XCD L2 is private, 4MB).
// Wave grid: 4x2 (wrow=(w&3)*32, wcol=(w>>2)*BN/2); 2xTJ frags per wave.
// mode 0: fp32 out | mode 1: relu -> bf16 out | mode 2: scatter q(scaled)/k/v
// ---------------------------------------------------------------------------
#define GBK 64

template <int BN, int GY>
__global__ __launch_bounds__(512) void mfma_gemm(
    const u16* __restrict__ A, const u16* __restrict__ W,
    const float* __restrict__ bias, float* __restrict__ outf,
    u16* __restrict__ outb, int M, int N, int K, int mode,
    u16* __restrict__ qb, u16* __restrict__ kb, u16* __restrict__ vb) {
  constexpr int TJ = BN / 32;            // B frag tiles per wave (4 or 2)
  __shared__ u16 As[2][128 * GBK];
  __shared__ u16 Bs[2][BN * GBK];
  int tid = threadIdx.x;
  int lane = tid & 63;
  int w = tid >> 6;                      // 0..7
  // XCD remap: lin%8 = XCD (round-robin heuristic); per XCD iterate j fastest
  int lin = blockIdx.y * 64 + blockIdx.x;
  int xcd = lin & 7, slot = lin >> 3;
  int jj = slot % GY;
  int mm = (slot / GY) * 8 + xcd;        // 0..63
  int m0 = mm * 128;
  int j0 = jj * BN;
  int wrow = (w & 3) * 32;
  int wcol = (w >> 2) * (BN / 2);
  int lm = lane & 15;
  int kq = lane >> 4;
  int sw = lm & 7;                       // read-side swizzle key (= row & 7)
  int r8 = lane >> 3;                    // staging row-within-seg
  int csrc = ((lane & 7) ^ r8) << 3;     // staging source col (u16), swizzled

  f32x4 acc[2][TJ];
#pragma unroll
  for (int i = 0; i < 2; i++)
#pragma unroll
    for (int j = 0; j < TJ; j++) acc[i][j] = (f32x4){0.f, 0.f, 0.f, 0.f};

  const u16* Ab = A + (size_t)m0 * K;
  const u16* Wb = W + (size_t)j0 * K;

  size_t soff[2];                        // per-wave staging offsets
#pragma unroll
  for (int u = 0; u < 2; u++)
    soff[u] = (size_t)(u * 64 + w * 8 + r8) * K + csrc;

  auto stage = [&](int kt, int pb) {
#pragma unroll
    for (int u = 0; u < 2; u++)          // A: 128 rows = 16 segs over 8 waves
      gl_lds16(&Ab[soff[u] + kt], &As[pb][(u * 8 + w) * 512]);
#pragma unroll
    for (int u = 0; u < TJ / 2; u++)     // B: BN rows
      gl_lds16(&Wb[soff[u] + kt], &Bs[pb][(u * 8 + w) * 512]);
  };

  stage(0, 0);
  int pb = 0;
  for (int kt = 0; kt < K; kt += GBK) {
    __syncthreads();                     // buf[pb] ready; buf[pb^1] reads done
    if (kt + GBK < K) stage(kt + GBK, pb ^ 1);
#pragma unroll
    for (int k2 = 0; k2 < GBK; k2 += 32) {
      int cc = ((((k2 >> 3) + kq) ^ sw) << 3);
      bf16x8 af[2], bfr[TJ];
#pragma unroll
      for (int t = 0; t < 2; t++)
        af[t] = *(const bf16x8*)&As[pb][(wrow + t * 16 + lm) * GBK + cc];
#pragma unroll
      for (int tj = 0; tj < TJ; tj++)
        bfr[tj] = *(const bf16x8*)&Bs[pb][(wcol + tj * 16 + lm) * GBK + cc];
#pragma unroll
      for (int ti = 0; ti < 2; ti++)
#pragma unroll
        for (int tj = 0; tj < TJ; tj++)
          acc[ti][tj] = __builtin_amdgcn_mfma_f32_16x16x32_bf16(
              af[ti], bfr[tj], acc[ti][tj], 0, 0, 0);
    }
    pb ^= 1;
  }

  // C/D layout: col=lane&15, row=(lane>>4)*4+reg
#pragma unroll
  for (int tj = 0; tj < TJ; tj++) {
    int n = j0 + wcol + tj * 16 + lm;
    float bv = bias[n];
#pragma unroll
    for (int ti = 0; ti < 2; ti++) {
#pragma unroll
      for (int r = 0; r < 4; r++) {
        int m = m0 + wrow + ti * 16 + kq * 4 + r;
        float val = acc[ti][tj][r] + bv;
        if (mode == 0) {
          outf[(size_t)m * N + n] = val;
        } else if (mode == 1) {
          outb[(size_t)m * N + n] = f2bf(fmaxf(val, 0.f));
        } else {
          int which = n >> 9, e = n & 511, h = e >> 6, d = e & 63;
          int s = m >> 2, b = m & 3;
          int bh = b * H_NUM + h;
          if (which == 0)       // q pre-scaled by 1/sqrt(hd)
            qb[((size_t)bh * S_LEN + s) * HD + d] = f2bf(val * 0.125f);
          else if (which == 1)
            kb[((size_t)bh * S_LEN + s) * HD + d] = f2bf(val);
          else                  // v contiguous (b,h,s,d); attn transposes in LDS
            vb[((size_t)bh * S_LEN + s) * HD + d] = f2bf(val);
        }
      }
    }
  }
}

// ---------------------------------------------------------------------------
// MFMA attention: block = 64 queries x (b,h); XCD remap groups all 32 i-tiles
// of 4 bh's per XCD (K+V working set 2MB -> L2-resident).
// ---------------------------------------------------------------------------
#define PST 72

__global__ __launch_bounds__(256) void attn_mfma_kernel(
    const u16* __restrict__ q, const u16* __restrict__ k,
    const u16* __restrict__ v, u16* __restrict__ yb) {
  __shared__ u16 Qs[64 * 64];   // [q][d] swizzled
  __shared__ u16 Ks[64 * 64];   // [c][d] swizzled
  __shared__ u16 Vs[64 * 64];   // [d][c] swizzled
  __shared__ u16 Ps[64 * PST];  // [q][c] bf16, pad-stride
  int tid = threadIdx.x, lane = tid & 63, w = tid >> 6;
  int quad = lane >> 4, lm = lane & 15;
  int sw = lm & 7;
  int r8 = lane >> 3;
  int csrc = ((lane & 7) ^ r8) << 3;
  // XCD remap over grid (32,32)
  int lin = blockIdx.y * 32 + blockIdx.x;
  int xcd = lin & 7, slot = lin >> 3;    // slot 0..127
  int bh = xcd * 4 + (slot >> 5);
  int i0 = (slot & 31) * 64;
  int b = bh >> 3, h = bh & 7;
  const u16* qp = q + ((size_t)bh * S_LEN + i0) * HD;
  const u16* kp = k + (size_t)bh * S_LEN * HD;
  const u16* vp = v + (size_t)bh * S_LEN * HD;

#pragma unroll
  for (int u = 0; u < 2; u++) {
    int seg = u * 4 + w;
    int r = seg * 8 + r8;
    gl_lds16(&qp[(size_t)r * HD + csrc], &Qs[seg * 512]);
  }

  int cl = i0 - WIN; if (cl < 0) cl = 0;
  int chi = i0 + 63 + WIN; if (chi > S_LEN - 1) chi = S_LEN - 1;
  int nch = (chi - cl + 64) >> 6;
  int tlo = (cl + 255) >> 8;
  int thi0 = (chi >> 8) + 1;
  int ng = tlo + 8 - thi0;

  float m_i[4], l_i[4];
  f32x4 o[4];
#pragma unroll
  for (int r = 0; r < 4; r++) { m_i[r] = -INFINITY; l_i[r] = 0.f; }
#pragma unroll
  for (int tj = 0; tj < 4; tj++) o[tj] = (f32x4){0.f, 0.f, 0.f, 0.f};

  for (int ch = 0; ch <= nch; ch++) {
    bool is_g = (ch == nch);
    int c0 = cl + (ch << 6);
    __syncthreads();
    if (!is_g) {
#pragma unroll
      for (int u = 0; u < 2; u++) {
        int seg = u * 4 + w;
        int r = seg * 8 + r8;
        gl_lds16(&kp[(size_t)(c0 + r) * HD + csrc], &Ks[seg * 512]);
      }
#pragma unroll
      for (int it = 0; it < 4; it++) {
        int flat = it * 256 + tid;
        int c = flat >> 4;
        int d0 = (flat & 15) << 2;
        ushort4 vv = make_ushort4(0, 0, 0, 0);
        int src = c0 + c;
        if (src <= chi) vv = *(const ushort4*)&vp[(size_t)src * HD + d0];
        u16 arr[4] = {vv.x, vv.y, vv.z, vv.w};
#pragma unroll
        for (int jd = 0; jd < 4; jd++) {
          int d = d0 + jd;
          Vs[d * 64 + ((((c >> 3) ^ (d & 7)) << 3) | (c & 7))] = arr[jd];
        }
      }
    } else {
      if (w == 0) {
        int rr = lane >> 3;
        int grow = (rr < tlo) ? (rr << 8) : ((thi0 + rr - tlo) << 8);
        if (rr >= ng) grow = 0;
        gl_lds16(&kp[(size_t)grow * HD + (((lane & 7) ^ rr) << 3)], &Ks[0]);
      }
      for (int e = tid; e < 64 * 8; e += 256) {
        int d = e & 63, cg = e >> 6;
        if (cg < ng) {
          int gs = (cg < tlo) ? (cg << 8) : ((thi0 + cg - tlo) << 8);
          Vs[d * 64 + ((d & 7) << 3) + cg] = vp[(size_t)gs * HD + d];
        }
      }
    }
    __syncthreads();

    f32x4 s[4];
#pragma unroll
    for (int tj = 0; tj < 4; tj++) s[tj] = (f32x4){0.f, 0.f, 0.f, 0.f};
#pragma unroll
    for (int k2 = 0; k2 < 64; k2 += 32) {
      int cb = (k2 >> 3) + quad;
      bf16x8 a = *(const bf16x8*)&Qs[(w * 16 + lm) * 64 + ((cb ^ sw) << 3)];
#pragma unroll
      for (int tj = 0; tj < 4; tj++) {
        bf16x8 bfr = *(const bf16x8*)&Ks[(tj * 16 + lm) * 64 + ((cb ^ sw) << 3)];
        s[tj] = __builtin_amdgcn_mfma_f32_16x16x32_bf16(a, bfr, s[tj], 0, 0, 0);
      }
    }
#pragma unroll
    for (int tj = 0; tj < 4; tj++) {
      int cidx = tj * 16 + lm;
      bool inval = is_g ? (cidx >= ng) : (c0 + cidx > chi);
      if (inval) {
        s[tj][0] = -INFINITY; s[tj][1] = -INFINITY;
        s[tj][2] = -INFINITY; s[tj][3] = -INFINITY;
      }
    }
#pragma unroll
    for (int r = 0; r < 4; r++) {
      float mx = fmaxf(fmaxf(s[0][r], s[1][r]), fmaxf(s[2][r], s[3][r]));
      mx = fmaxf(mx, __shfl_xor(mx, 1)); mx = fmaxf(mx, __shfl_xor(mx, 2));
      mx = fmaxf(mx, __shfl_xor(mx, 4)); mx = fmaxf(mx, __shfl_xor(mx, 8));
      float mnew = fmaxf(m_i[r], mx);
      float al = __expf(m_i[r] - mnew);
      float rs = 0.f;
#pragma unroll
      for (int tj = 0; tj < 4; tj++) {
        float p = __expf(s[tj][r] - mnew);
        s[tj][r] = p; rs += p;
      }
      rs += __shfl_xor(rs, 1); rs += __shfl_xor(rs, 2);
      rs += __shfl_xor(rs, 4); rs += __shfl_xor(rs, 8);
      l_i[r] = l_i[r] * al + rs;
      m_i[r] = mnew;
      o[0][r] *= al; o[1][r] *= al; o[2][r] *= al; o[3][r] *= al;
    }
#pragma unroll
    for (int tj = 0; tj < 4; tj++)
#pragma unroll
      for (int r = 0; r < 4; r++)
        Ps[(w * 16 + quad * 4 + r) * PST + tj * 16 + lm] = f2bf(s[tj][r]);
#pragma unroll
    for (int k2 = 0; k2 < 64; k2 += 32) {
      int cb = (k2 >> 3) + quad;
      bf16x8 a = *(const bf16x8*)&Ps[(w * 16 + lm) * PST + k2 + quad * 8];
#pragma unroll
      for (int tj = 0; tj < 4; tj++) {
        bf16x8 bfr = *(const bf16x8*)&Vs[(tj * 16 + lm) * 64 + ((cb ^ sw) << 3)];
        o[tj] = __builtin_amdgcn_mfma_f32_16x16x32_bf16(a, bfr, o[tj], 0, 0, 0);
      }
    }
  }

#pragma unroll
  for (int r = 0; r < 4; r++) {
    int sg = i0 + w * 16 + quad * 4 + r;
    float inv = 1.f / l_i[r];
#pragma unroll
    for (int tj = 0; tj < 4; tj++) {
      int d = tj * 16 + lm;
      yb[((size_t)sg * B_SZ + b) * E_DIM + h * HD + d] = f2bf(o[tj][r] * inv);
    }
  }
}

// ---------------------------------------------------------------------------
// residual add + LayerNorm; optional bf16 secondary output
// ---------------------------------------------------------------------------
__global__ __launch_bounds__(256) void add_ln_kernel(
    const float* __restrict__ a, const float* __restrict__ r,
    const float* __restrict__ g, const float* __restrict__ be,
    float* __restrict__ out, u16* __restrict__ outb) {
  int wave = threadIdx.x >> 6;
  int lane = threadIdx.x & 63;
  int row = blockIdx.x * 4 + wave;
  const float* ar = a + (size_t)row * E_DIM;
  const float* rr = r + (size_t)row * E_DIM;
  float vals[8];
  float s = 0.f;
#pragma unroll
  for (int t = 0; t < 8; t++) {
    vals[t] = ar[t * 64 + lane] + rr[t * 64 + lane];
    s += vals[t];
  }
#pragma unroll
  for (int o = 32; o >= 1; o >>= 1) s += __shfl_xor(s, o, 64);
  float mu = s * (1.f / E_DIM);
  float vs = 0.f;
#pragma unroll
  for (int t = 0; t < 8; t++) { float d = vals[t] - mu; vs += d * d; }
#pragma unroll
  for (int o = 32; o >= 1; o >>= 1) vs += __shfl_xor(vs, o, 64);
  float inv = rsqrtf(vs * (1.f / E_DIM) + 1e-5f);
  float* orow = out + (size_t)row * E_DIM;
  u16* obrow = outb ? outb + (size_t)row * E_DIM : nullptr;
#pragma unroll
  for (int t = 0; t < 8; t++) {
    int e = t * 64 + lane;
    float val = (vals[t] - mu) * inv * g[e] + be[e];
    orow[e] = val;
    if (obrow) obrow[e] = f2bf(val);
  }
}

// ---------------------------------------------------------------------------
// launch
// ---------------------------------------------------------------------------
extern "C" void kernel_launch(void* const* d_in, const int* in_sizes, int n_in,
                              void* d_out, int out_size, void* d_ws, size_t ws_size,
                              hipStream_t stream) {
  const float* x     = (const float*)d_in[0];
  const float* pos   = (const float*)d_in[1];
  const float* in_w  = (const float*)d_in[2];
  const float* in_b  = (const float*)d_in[3];
  const float* out_w = (const float*)d_in[4];
  const float* out_b = (const float*)d_in[5];
  const float* w1    = (const float*)d_in[6];
  const float* b1    = (const float*)d_in[7];
  const float* w2    = (const float*)d_in[8];
  const float* b2    = (const float*)d_in[9];
  const float* g1    = (const float*)d_in[10];
  const float* be1   = (const float*)d_in[11];
  const float* g2    = (const float*)d_in[12];
  const float* be2   = (const float*)d_in[13];
  float* out = (float*)d_out;

  char* base = (char*)d_ws;
  float* xp    = (float*)(base);
  u16*   xpb   = (u16*)(base + ((size_t)16 << 20));
  u16*   qb    = (u16*)(base + ((size_t)24 << 20));
  u16*   kb    = (u16*)(base + ((size_t)32 << 20));
  u16*   vb    = (u16*)(base + ((size_t)40 << 20));
  u16*   ybf   = (u16*)(base + ((size_t)48 << 20));
  float* aprj  = (float*)(base + ((size_t)56 << 20));
  u16*   inwb  = (u16*)(base + ((size_t)72 << 20));
  u16*   outwb = (u16*)(base + ((size_t)74 << 20));
  u16*   w1b   = (u16*)(base + ((size_t)76 << 20));
  u16*   w2b   = (u16*)(base + ((size_t)78 << 20));
  float* x1    = xp;
  u16*   x1b   = xpb;
  u16*   ff1b  = qb;      // 24M..56M
  float* ff2   = aprj;

  wcast_kernel<<<3072, 256, 0, stream>>>(in_w, out_w, w1, w2, inwb, outwb, w1b, w2b);
  add_pos_kernel<<<4096, 256, 0, stream>>>(x, pos, xp, xpb);
  mfma_gemm<128, 12><<<dim3(64, 12), 512, 0, stream>>>(xpb, inwb, in_b, nullptr, nullptr,
                                                       NROWS, 1536, 512, 2, qb, kb, vb);
  attn_mfma_kernel<<<dim3(32, 32), 256, 0, stream>>>(qb, kb, vb, ybf);
  mfma_gemm<64, 8><<<dim3(64, 8), 512, 0, stream>>>(ybf, outwb, out_b, aprj, nullptr,
                                                    NROWS, 512, 512, 0, nullptr, nullptr, nullptr);
  add_ln_kernel<<<2048, 256, 0, stream>>>(xp, aprj, g1, be1, x1, x1b);
  mfma_gemm<128, 16><<<dim3(64, 16), 512, 0, stream>>>(x1b, w1b, b1, nullptr, ff1b,
                                                       NROWS, 2048, 512, 1, nullptr, nullptr, nullptr);
  mfma_gemm<64, 8><<<dim3(64, 8), 512, 0, stream>>>(ff1b, w2b, b2, ff2, nullptr,
                                                    NROWS, 512, 2048, 0, nullptr, nullptr, nullptr);
  add_ln_kernel<<<2048, 256, 0, stream>>>(x1, ff2, g2, be2, out, nullptr);
}

// Round 7
// 247.704 us; speedup vs baseline: 5.7774x; 1.0807x over previous
//
#include <hip/hip_runtime.h>
#include <hip/hip_bf16.h>
#include <math.h>

#define S_LEN 2048
#define B_SZ  4
#define E_DIM 512
#define H_NUM 8
#define HD    64
#define FF_DIM 2048
#define NROWS 8192
#define WIN   128

typedef unsigned short u16;
typedef __bf16 bf16x8 __attribute__((ext_vector_type(8)));
typedef float  f32x4  __attribute__((ext_vector_type(4)));

// fp32 -> bf16 round-to-nearest-even
__device__ __forceinline__ u16 f2bf(float f) {
  union { float f; unsigned u; } v; v.f = f;
  unsigned u = v.u;
  return (u16)((u + 0x7fffu + ((u >> 16) & 1u)) >> 16);
}

// async global->LDS, 16B per lane; LDS dest = wave-uniform base + lane*16
__device__ __forceinline__ void gl_lds16(const u16* gp, u16* lp) {
  __builtin_amdgcn_global_load_lds(
      (const __attribute__((address_space(1))) unsigned int*)gp,
      (__attribute__((address_space(3))) unsigned int*)lp, 16, 0, 0);
}

// ---------------------------------------------------------------------------
// weight cast: 4 fp32 matrices -> bf16
// ---------------------------------------------------------------------------
__global__ __launch_bounds__(256) void wcast_kernel(
    const float* __restrict__ s0, const float* __restrict__ s1,
    const float* __restrict__ s2, const float* __restrict__ s3,
    u16* __restrict__ d0, u16* __restrict__ d1,
    u16* __restrict__ d2, u16* __restrict__ d3) {
  const int n0 = 196608, n1 = 65536, n2 = 262144;
  int i = blockIdx.x * blockDim.x + threadIdx.x;
  const float4* sp; ushort4* dp; int off;
  if (i < n0)                { sp = (const float4*)s0; dp = (ushort4*)d0; off = i; }
  else if (i < n0 + n1)      { sp = (const float4*)s1; dp = (ushort4*)d1; off = i - n0; }
  else if (i < n0 + n1 + n2) { sp = (const float4*)s2; dp = (ushort4*)d2; off = i - n0 - n1; }
  else                       { sp = (const float4*)s3; dp = (ushort4*)d3; off = i - n0 - n1 - n2; }
  float4 v = sp[off];
  ushort4 o; o.x = f2bf(v.x); o.y = f2bf(v.y); o.z = f2bf(v.z); o.w = f2bf(v.w);
  dp[off] = o;
}

// ---------------------------------------------------------------------------
// x + pos (pos[:, :B, :] broadcast over seq) -> fp32 + bf16 copies
// ---------------------------------------------------------------------------
__global__ __launch_bounds__(256) void add_pos_kernel(
    const float* __restrict__ x, const float* __restrict__ pos,
    float* __restrict__ xp, u16* __restrict__ xpb) {
  int idx = blockIdx.x * blockDim.x + threadIdx.x;
  float4 xv = ((const float4*)x)[idx];
  float4 pv = ((const float4*)pos)[idx & 511];
  float4 o;
  o.x = xv.x + pv.x; o.y = xv.y + pv.y; o.z = xv.z + pv.z; o.w = xv.w + pv.w;
  ((float4*)xp)[idx] = o;
  ushort4 ob; ob.x = f2bf(o.x); ob.y = f2bf(o.y); ob.z = f2bf(o.z); ob.w = f2bf(o.w);
  ((ushort4*)xpb)[idx] = ob;
}

// ---------------------------------------------------------------------------
// bf16 MFMA GEMM: 128xBN tile, BK=64, 256 threads (4 waves), XOR-swizzled LDS,
// double-buffered staging via global_load_lds, XCD-aware block remap, and
// COALESCED epilogue: acc -> LDS (staging buffers are dead) -> 16B row-major
// global stores. mode 0: fp32 | mode 1: relu->bf16 | mode 2: q(scaled)/k/v
// ---------------------------------------------------------------------------
#define GBK 64

template <int BN, int GY>
__global__ __launch_bounds__(256) void mfma_gemm(
    const u16* __restrict__ A, const u16* __restrict__ W,
    const float* __restrict__ bias, float* __restrict__ outf,
    u16* __restrict__ outb, int M, int N, int K, int mode,
    u16* __restrict__ qb, u16* __restrict__ kb, u16* __restrict__ vb) {
  constexpr int TJ = BN / 32;            // B frag tiles per wave
  __shared__ u16 SMEM[2 * 128 * GBK + 2 * BN * GBK];
  u16* As0 = SMEM;
  u16* Bs0 = SMEM + 2 * 128 * GBK;
  int tid = threadIdx.x;
  int lane = tid & 63;
  int w = tid >> 6;                      // 0..3
  // XCD remap: lin%8 = XCD; per XCD iterate j fastest (A-tile L2 locality)
  int lin = blockIdx.y * 64 + blockIdx.x;
  int xcd = lin & 7, slot = lin >> 3;
  int jj = slot % GY;
  int mm = (slot / GY) * 8 + xcd;
  int m0 = mm * 128;
  int j0 = jj * BN;
  int wrow = (w >> 1) * 64;
  int wcol = (w & 1) * (BN / 2);
  int lm = lane & 15;
  int kq = lane >> 4;
  int sw = lm & 7;
  int r8 = lane >> 3;
  int csrc = ((lane & 7) ^ r8) << 3;

  f32x4 acc[4][TJ];
#pragma unroll
  for (int i = 0; i < 4; i++)
#pragma unroll
    for (int j = 0; j < TJ; j++) acc[i][j] = (f32x4){0.f, 0.f, 0.f, 0.f};

  const u16* Ab = A + (size_t)m0 * K;
  const u16* Wb = W + (size_t)j0 * K;

  size_t soff[4];
#pragma unroll
  for (int u = 0; u < 4; u++)
    soff[u] = (size_t)(u * 32 + w * 8 + r8) * K + csrc;

  auto stage = [&](int kt, int pb) {
#pragma unroll
    for (int u = 0; u < 4; u++)
      gl_lds16(&Ab[soff[u] + kt], &As0[pb * 128 * GBK + (u * 4 + w) * 512]);
#pragma unroll
    for (int u = 0; u < TJ; u++)
      gl_lds16(&Wb[soff[u] + kt], &Bs0[pb * BN * GBK + (u * 4 + w) * 512]);
  };

  stage(0, 0);
  int pb = 0;
  for (int kt = 0; kt < K; kt += GBK) {
    __syncthreads();                     // buf[pb] ready; buf[pb^1] reads done
    if (kt + GBK < K) stage(kt + GBK, pb ^ 1);
#pragma unroll
    for (int k2 = 0; k2 < GBK; k2 += 32) {
      int cc = ((((k2 >> 3) + kq) ^ sw) << 3);
      bf16x8 af[4], bfr[TJ];
#pragma unroll
      for (int t = 0; t < 4; t++)
        af[t] = *(const bf16x8*)&As0[pb * 128 * GBK + (wrow + t * 16 + lm) * GBK + cc];
#pragma unroll
      for (int tj = 0; tj < TJ; tj++)
        bfr[tj] = *(const bf16x8*)&Bs0[pb * BN * GBK + (wcol + tj * 16 + lm) * GBK + cc];
#pragma unroll
      for (int ti = 0; ti < 4; ti++)
#pragma unroll
        for (int tj = 0; tj < TJ; tj++)
          acc[ti][tj] = __builtin_amdgcn_mfma_f32_16x16x32_bf16(
              af[ti], bfr[tj], acc[ti][tj], 0, 0, 0);
    }
    pb ^= 1;
  }

  __syncthreads();                       // K-loop LDS reads done; SMEM reusable
  // C/D layout: col=lane&15, row=(lane>>4)*4+reg
  if (mode == 0) {
    float* Cf = (float*)SMEM;
    constexpr int CF = BN + 4;           // bank-shifted fp32 stride
#pragma unroll
    for (int p = 0; p < 2; p++) {        // two 64-row passes (LDS capacity)
      if ((w >> 1) == p) {
#pragma unroll
        for (int tj = 0; tj < TJ; tj++) {
          float bv = bias[j0 + wcol + tj * 16 + lm];
#pragma unroll
          for (int ti = 0; ti < 4; ti++)
#pragma unroll
            for (int r = 0; r < 4; r++)
              Cf[(ti * 16 + kq * 4 + r) * CF + wcol + tj * 16 + lm] =
                  acc[ti][tj][r] + bv;
        }
      }
      __syncthreads();
      constexpr int RC4 = BN / 4;        // float4 chunks per row
#pragma unroll
      for (int it = 0; it < 64 * RC4 / 256; it++) {
        int id = it * 256 + tid;
        int row = id / RC4, c4 = (id % RC4) * 4;
        float4 vq = *(float4*)&Cf[row * CF + c4];
        *(float4*)&outf[(size_t)(m0 + p * 64 + row) * N + j0 + c4] = vq;
      }
      __syncthreads();
    }
  } else {
    u16* Cs = (u16*)SMEM;
    constexpr int CS = BN + 8;           // bank-shifted u16 stride
    int which = j0 >> 9;
    float qsc = (mode == 2 && which == 0) ? 0.125f : 1.f;
#pragma unroll
    for (int tj = 0; tj < TJ; tj++) {
      float bv = bias[j0 + wcol + tj * 16 + lm];
#pragma unroll
      for (int ti = 0; ti < 4; ti++)
#pragma unroll
        for (int r = 0; r < 4; r++) {
          float val = acc[ti][tj][r] + bv;
          if (mode == 1) val = fmaxf(val, 0.f);
          Cs[(wrow + ti * 16 + kq * 4 + r) * CS + wcol + tj * 16 + lm] =
              f2bf(val * qsc);
        }
    }
    __syncthreads();
    constexpr int RC8 = BN / 8;          // 16B chunks per row
#pragma unroll
    for (int it = 0; it < 128 * RC8 / 256; it++) {
      int id = it * 256 + tid;
      int row = id / RC8, c8 = (id % RC8) * 8;
      uint4 vq = *(uint4*)&Cs[row * CS + c8];
      if (mode == 1) {
        *(uint4*)&outb[(size_t)(m0 + row) * N + j0 + c8] = vq;
      } else {
        int e = (j0 & 511) + c8;
        int h = e >> 6, d0 = e & 63;
        int m = m0 + row, s = m >> 2, b = m & 3;
        u16* dst = (which == 0) ? qb : (which == 1) ? kb : vb;
        *(uint4*)&dst[((size_t)(b * H_NUM + h) * S_LEN + s) * HD + d0] = vq;
      }
    }
  }
}

// ---------------------------------------------------------------------------
// MFMA attention: block = 64 queries x (b,h); XCD remap; coalesced epilogue
// via Qs reuse.
// ---------------------------------------------------------------------------
#define PST 72

__global__ __launch_bounds__(256) void attn_mfma_kernel(
    const u16* __restrict__ q, const u16* __restrict__ k,
    const u16* __restrict__ v, u16* __restrict__ yb) {
  __shared__ u16 Qs[64 * 64];   // [q][d] swizzled; reused for O epilogue
  __shared__ u16 Ks[64 * 64];   // [c][d] swizzled
  __shared__ u16 Vs[64 * 64];   // [d][c] swizzled
  __shared__ u16 Ps[64 * PST];  // [q][c] bf16, pad-stride
  int tid = threadIdx.x, lane = tid & 63, w = tid >> 6;
  int quad = lane >> 4, lm = lane & 15;
  int sw = lm & 7;
  int r8 = lane >> 3;
  int csrc = ((lane & 7) ^ r8) << 3;
  int lin = blockIdx.y * 32 + blockIdx.x;
  int xcd = lin & 7, slot = lin >> 3;
  int bh = xcd * 4 + (slot >> 5);
  int i0 = (slot & 31) * 64;
  int b = bh >> 3, h = bh & 7;
  const u16* qp = q + ((size_t)bh * S_LEN + i0) * HD;
  const u16* kp = k + (size_t)bh * S_LEN * HD;
  const u16* vp = v + (size_t)bh * S_LEN * HD;

#pragma unroll
  for (int u = 0; u < 2; u++) {
    int seg = u * 4 + w;
    int r = seg * 8 + r8;
    gl_lds16(&qp[(size_t)r * HD + csrc], &Qs[seg * 512]);
  }

  int cl = i0 - WIN; if (cl < 0) cl = 0;
  int chi = i0 + 63 + WIN; if (chi > S_LEN - 1) chi = S_LEN - 1;
  int nch = (chi - cl + 64) >> 6;
  int tlo = (cl + 255) >> 8;
  int thi0 = (chi >> 8) + 1;
  int ng = tlo + 8 - thi0;

  float m_i[4], l_i[4];
  f32x4 o[4];
#pragma unroll
  for (int r = 0; r < 4; r++) { m_i[r] = -INFINITY; l_i[r] = 0.f; }
#pragma unroll
  for (int tj = 0; tj < 4; tj++) o[tj] = (f32x4){0.f, 0.f, 0.f, 0.f};

  for (int ch = 0; ch <= nch; ch++) {
    bool is_g = (ch == nch);
    int c0 = cl + (ch << 6);
    __syncthreads();
    if (!is_g) {
#pragma unroll
      for (int u = 0; u < 2; u++) {
        int seg = u * 4 + w;
        int r = seg * 8 + r8;
        gl_lds16(&kp[(size_t)(c0 + r) * HD + csrc], &Ks[seg * 512]);
      }
#pragma unroll
      for (int it = 0; it < 4; it++) {
        int flat = it * 256 + tid;
        int c = flat >> 4;
        int d0 = (flat & 15) << 2;
        ushort4 vv = make_ushort4(0, 0, 0, 0);
        int src = c0 + c;
        if (src <= chi) vv = *(const ushort4*)&vp[(size_t)src * HD + d0];
        u16 arr[4] = {vv.x, vv.y, vv.z, vv.w};
#pragma unroll
        for (int jd = 0; jd < 4; jd++) {
          int d = d0 + jd;
          Vs[d * 64 + ((((c >> 3) ^ (d & 7)) << 3) | (c & 7))] = arr[jd];
        }
      }
    } else {
      if (w == 0) {
        int rr = lane >> 3;
        int grow = (rr < tlo) ? (rr << 8) : ((thi0 + rr - tlo) << 8);
        if (rr >= ng) grow = 0;
        gl_lds16(&kp[(size_t)grow * HD + (((lane & 7) ^ rr) << 3)], &Ks[0]);
      }
      for (int e = tid; e < 64 * 8; e += 256) {
        int d = e & 63, cg = e >> 6;
        if (cg < ng) {
          int gs = (cg < tlo) ? (cg << 8) : ((thi0 + cg - tlo) << 8);
          Vs[d * 64 + ((d & 7) << 3) + cg] = vp[(size_t)gs * HD + d];
        }
      }
    }
    __syncthreads();

    f32x4 s[4];
#pragma unroll
    for (int tj = 0; tj < 4; tj++) s[tj] = (f32x4){0.f, 0.f, 0.f, 0.f};
#pragma unroll
    for (int k2 = 0; k2 < 64; k2 += 32) {
      int cb = (k2 >> 3) + quad;
      bf16x8 a = *(const bf16x8*)&Qs[(w * 16 + lm) * 64 + ((cb ^ sw) << 3)];
#pragma unroll
      for (int tj = 0; tj < 4; tj++) {
        bf16x8 bfr = *(const bf16x8*)&Ks[(tj * 16 + lm) * 64 + ((cb ^ sw) << 3)];
        s[tj] = __builtin_amdgcn_mfma_f32_16x16x32_bf16(a, bfr, s[tj], 0, 0, 0);
      }
    }
#pragma unroll
    for (int tj = 0; tj < 4; tj++) {
      int cidx = tj * 16 + lm;
      bool inval = is_g ? (cidx >= ng) : (c0 + cidx > chi);
      if (inval) {
        s[tj][0] = -INFINITY; s[tj][1] = -INFINITY;
        s[tj][2] = -INFINITY; s[tj][3] = -INFINITY;
      }
    }
#pragma unroll
    for (int r = 0; r < 4; r++) {
      float mx = fmaxf(fmaxf(s[0][r], s[1][r]), fmaxf(s[2][r], s[3][r]));
      mx = fmaxf(mx, __shfl_xor(mx, 1)); mx = fmaxf(mx, __shfl_xor(mx, 2));
      mx = fmaxf(mx, __shfl_xor(mx, 4)); mx = fmaxf(mx, __shfl_xor(mx, 8));
      float mnew = fmaxf(m_i[r], mx);
      float al = __expf(m_i[r] - mnew);
      float rs = 0.f;
#pragma unroll
      for (int tj = 0; tj < 4; tj++) {
        float p = __expf(s[tj][r] - mnew);
        s[tj][r] = p; rs += p;
      }
      rs += __shfl_xor(rs, 1); rs += __shfl_xor(rs, 2);
      rs += __shfl_xor(rs, 4); rs += __shfl_xor(rs, 8);
      l_i[r] = l_i[r] * al + rs;
      m_i[r] = mnew;
      o[0][r] *= al; o[1][r] *= al; o[2][r] *= al; o[3][r] *= al;
    }
#pragma unroll
    for (int tj = 0; tj < 4; tj++)
#pragma unroll
      for (int r = 0; r < 4; r++)
        Ps[(w * 16 + quad * 4 + r) * PST + tj * 16 + lm] = f2bf(s[tj][r]);
#pragma unroll
    for (int k2 = 0; k2 < 64; k2 += 32) {
      int cb = (k2 >> 3) + quad;
      bf16x8 a = *(const bf16x8*)&Ps[(w * 16 + lm) * PST + k2 + quad * 8];
#pragma unroll
      for (int tj = 0; tj < 4; tj++) {
        bf16x8 bfr = *(const bf16x8*)&Vs[(tj * 16 + lm) * 64 + ((cb ^ sw) << 3)];
        o[tj] = __builtin_amdgcn_mfma_f32_16x16x32_bf16(a, bfr, o[tj], 0, 0, 0);
      }
    }
  }

  // coalesced epilogue: O -> Qs (dead) -> 16B row stores
  __syncthreads();
#pragma unroll
  for (int r = 0; r < 4; r++) {
    float inv = 1.f / l_i[r];
#pragma unroll
    for (int tj = 0; tj < 4; tj++)
      Qs[(w * 16 + quad * 4 + r) * 64 + tj * 16 + lm] = f2bf(o[tj][r] * inv);
  }
  __syncthreads();
#pragma unroll
  for (int it = 0; it < 2; it++) {
    int id = it * 256 + tid;
    int row = id >> 3, c8 = (id & 7) * 8;
    uint4 vq = *(uint4*)&Qs[row * 64 + c8];
    *(uint4*)&yb[((size_t)(i0 + row) * B_SZ + b) * E_DIM + h * HD + c8] = vq;
  }
}

// ---------------------------------------------------------------------------
// residual add + LayerNorm; optional bf16 secondary output
// ---------------------------------------------------------------------------
__global__ __launch_bounds__(256) void add_ln_kernel(
    const float* __restrict__ a, const float* __restrict__ r,
    const float* __restrict__ g, const float* __restrict__ be,
    float* __restrict__ out, u16* __restrict__ outb) {
  int wave = threadIdx.x >> 6;
  int lane = threadIdx.x & 63;
  int row = blockIdx.x * 4 + wave;
  const float* ar = a + (size_t)row * E_DIM;
  const float* rr = r + (size_t)row * E_DIM;
  float vals[8];
  float s = 0.f;
#pragma unroll
  for (int t = 0; t < 8; t++) {
    vals[t] = ar[t * 64 + lane] + rr[t * 64 + lane];
    s += vals[t];
  }
#pragma unroll
  for (int o = 32; o >= 1; o >>= 1) s += __shfl_xor(s, o, 64);
  float mu = s * (1.f / E_DIM);
  float vs = 0.f;
#pragma unroll
  for (int t = 0; t < 8; t++) { float d = vals[t] - mu; vs += d * d; }
#pragma unroll
  for (int o = 32; o >= 1; o >>= 1) vs += __shfl_xor(vs, o, 64);
  float inv = rsqrtf(vs * (1.f / E_DIM) + 1e-5f);
  float* orow = out + (size_t)row * E_DIM;
  u16* obrow = outb ? outb + (size_t)row * E_DIM : nullptr;
#pragma unroll
  for (int t = 0; t < 8; t++) {
    int e = t * 64 + lane;
    float val = (vals[t] - mu) * inv * g[e] + be[e];
    orow[e] = val;
    if (obrow) obrow[e] = f2bf(val);
  }
}

// ---------------------------------------------------------------------------
// launch
// ---------------------------------------------------------------------------
extern "C" void kernel_launch(void* const* d_in, const int* in_sizes, int n_in,
                              void* d_out, int out_size, void* d_ws, size_t ws_size,
                              hipStream_t stream) {
  const float* x     = (const float*)d_in[0];
  const float* pos   = (const float*)d_in[1];
  const float* in_w  = (const float*)d_in[2];
  const float* in_b  = (const float*)d_in[3];
  const float* out_w = (const float*)d_in[4];
  const float* out_b = (const float*)d_in[5];
  const float* w1    = (const float*)d_in[6];
  const float* b1    = (const float*)d_in[7];
  const float* w2    = (const float*)d_in[8];
  const float* b2    = (const float*)d_in[9];
  const float* g1    = (const float*)d_in[10];
  const float* be1   = (const float*)d_in[11];
  const float* g2    = (const float*)d_in[12];
  const float* be2   = (const float*)d_in[13];
  float* out = (float*)d_out;

  char* base = (char*)d_ws;
  float* xp    = (float*)(base);
  u16*   xpb   = (u16*)(base + ((size_t)16 << 20));
  u16*   qb    = (u16*)(base + ((size_t)24 << 20));
  u16*   kb    = (u16*)(base + ((size_t)32 << 20));
  u16*   vb    = (u16*)(base + ((size_t)40 << 20));
  u16*   ybf   = (u16*)(base + ((size_t)48 << 20));
  float* aprj  = (float*)(base + ((size_t)56 << 20));
  u16*   inwb  = (u16*)(base + ((size_t)72 << 20));
  u16*   outwb = (u16*)(base + ((size_t)74 << 20));
  u16*   w1b   = (u16*)(base + ((size_t)76 << 20));
  u16*   w2b   = (u16*)(base + ((size_t)78 << 20));
  float* x1    = xp;
  u16*   x1b   = xpb;
  u16*   ff1b  = qb;      // 24M..56M
  float* ff2   = aprj;

  wcast_kernel<<<3072, 256, 0, stream>>>(in_w, out_w, w1, w2, inwb, outwb, w1b, w2b);
  add_pos_kernel<<<4096, 256, 0, stream>>>(x, pos, xp, xpb);
  mfma_gemm<128, 12><<<dim3(64, 12), 256, 0, stream>>>(xpb, inwb, in_b, nullptr, nullptr,
                                                       NROWS, 1536, 512, 2, qb, kb, vb);
  attn_mfma_kernel<<<dim3(32, 32), 256, 0, stream>>>(qb, kb, vb, ybf);
  mfma_gemm<64, 8><<<dim3(64, 8), 256, 0, stream>>>(ybf, outwb, out_b, aprj, nullptr,
                                                    NROWS, 512, 512, 0, nullptr, nullptr, nullptr);
  add_ln_kernel<<<2048, 256, 0, stream>>>(xp, aprj, g1, be1, x1, x1b);
  mfma_gemm<128, 16><<<dim3(64, 16), 256, 0, stream>>>(x1b, w1b, b1, nullptr, ff1b,
                                                       NROWS, 2048, 512, 1, nullptr, nullptr, nullptr);
  mfma_gemm<64, 8><<<dim3(64, 8), 256, 0, stream>>>(ff1b, w2b, b2, ff2, nullptr,
                                                    NROWS, 512, 2048, 0, nullptr, nullptr, nullptr);
  add_ln_kernel<<<2048, 256, 0, stream>>>(x1, ff2, g2, be2, out, nullptr);
}